// Round 4
// baseline (684.186 us; speedup 1.0000x reference)
//
#include <hip/hip_runtime.h>

typedef _Float16 f16;
typedef __attribute__((ext_vector_type(4))) _Float16 half4;
typedef __attribute__((ext_vector_type(8))) _Float16 half8;
typedef __attribute__((ext_vector_type(4))) float f32x4;
typedef unsigned short u16;

#define MFMA32(a,b,c) __builtin_amdgcn_mfma_f32_16x16x32_f16(a,b,c,0,0,0)
#define MFMA16(a,b,c) __builtin_amdgcn_mfma_f32_16x16x16f16(a,b,c,0,0,0)

// ws layout (f16 element offsets)
#define W_IN0   0
#define W_OUT0  196608
#define W_PROJ0 262144
#define X0      327680
#define QK0     33882112ull
#define VT0     100990976ull

// ---------------- k0: cast weights to f16 ----------------
__global__ void k0_cast(const float* __restrict__ iw, const float* __restrict__ ow,
                        const float* __restrict__ pw, f16* __restrict__ W) {
    int i = blockIdx.x * 256 + threadIdx.x;
    if (i < 196608) W[W_IN0 + i] = (f16)iw[i];
    if (i < 65536) {
        W[W_OUT0 + i]  = (f16)ow[i];
        W[W_PROJ0 + i] = (f16)pw[i];
    }
}

// ---------------- k1: NCHW gather + LayerNorm -> X[t][256] f16 (no LDS, float4 loads) ----------------
// lane = (cg channel-group, wl4 w-quad); wave = hh row. Each global load is float4 along w
// (4 tokens x 1 channel), fully coalesced 128B per 8-lane group. LN stats per-token in regs,
// reduced over the 8 channel-groups via shfl_xor(8/16/32).
__global__ __launch_bounds__(256, 4)
void k1_pack(const float* __restrict__ feat, const float* __restrict__ lnw,
             const float* __restrict__ lnb, f16* __restrict__ X) {
    const int tid = threadIdx.x, lane = tid & 63, hh = tid >> 6;
    const int bid = blockIdx.x;
    const int jh = bid & 3, wi = (bid >> 2) & 31, bb = bid >> 7;
    const int h0 = wi * 4, w0 = jh * 32;
    const int wl4 = lane & 7, cg = lane >> 3;
    const int h = h0 + hh, wb = w0 + wl4 * 4;
    const bool hok = (h < 127);
    const bool edge = (wb + 3) >= 127;      // only jh==3 && wl4==7 (w=127 is pad)
    const size_t bbase = (size_t)bb * (256 * 127 * 127);
    const int c0 = cg * 32;
    const float* p0 = feat + bbase + (size_t)c0 * 16129 + (size_t)h * 127 + wb;

    half4 arr[32];                           // [ch within group][token e], f16 pre-LN
    float ss[4] = {0.f, 0.f, 0.f, 0.f}, qq[4] = {0.f, 0.f, 0.f, 0.f};
    if (hok && !edge) {
#pragma unroll 8
        for (int i = 0; i < 32; ++i) {
            f32x4 v = *(const f32x4*)(p0 + (size_t)i * 16129);
            half4 hv;
#pragma unroll
            for (int e = 0; e < 4; ++e) { ss[e] += v[e]; qq[e] += v[e] * v[e]; hv[e] = (f16)v[e]; }
            arr[i] = hv;
        }
    } else if (hok) {
#pragma unroll 8
        for (int i = 0; i < 32; ++i) {
            const float* pi = p0 + (size_t)i * 16129;
            half4 hv;
#pragma unroll
            for (int e = 0; e < 3; ++e) { float v = pi[e]; ss[e] += v; qq[e] += v * v; hv[e] = (f16)v; }
            hv[3] = (f16)0.f;
            arr[i] = hv;
        }
    } else {
#pragma unroll
        for (int i = 0; i < 32; ++i) {
            half4 hv; hv[0] = hv[1] = hv[2] = hv[3] = (f16)0.f; arr[i] = hv;
        }
    }
#pragma unroll
    for (int e = 0; e < 4; ++e) {
        ss[e] += __shfl_xor(ss[e], 8);  qq[e] += __shfl_xor(qq[e], 8);
        ss[e] += __shfl_xor(ss[e], 16); qq[e] += __shfl_xor(qq[e], 16);
        ss[e] += __shfl_xor(ss[e], 32); qq[e] += __shfl_xor(qq[e], 32);
    }
    float mu[4], rs[4];
#pragma unroll
    for (int e = 0; e < 4; ++e) {
        mu[e] = ss[e] * (1.f / 256.f);
        rs[e] = rsqrtf(qq[e] * (1.f / 256.f) - mu[e] * mu[e] + 1e-5f);
    }
#pragma unroll
    for (int q = 0; q < 4; ++q) {
        f32x4 lw0 = *(const f32x4*)(lnw + c0 + q * 8);
        f32x4 lw1 = *(const f32x4*)(lnw + c0 + q * 8 + 4);
        f32x4 lb0 = *(const f32x4*)(lnb + c0 + q * 8);
        f32x4 lb1 = *(const f32x4*)(lnb + c0 + q * 8 + 4);
#pragma unroll
        for (int e = 0; e < 4; ++e) {
            const int m = wl4 * 16 + hh * 4 + e;
            f16* xrow = X + ((size_t)bid * 128 + m) * 256 + c0;
            half8 o;
#pragma unroll
            for (int j = 0; j < 4; ++j) {
                o[j]     = (f16)(((float)arr[q * 8 + j][e]     - mu[e]) * rs[e] * lw0[j] + lb0[j]);
                o[j + 4] = (f16)(((float)arr[q * 8 + j + 4][e] - mu[e]) * rs[e] * lw1[j] + lb1[j]);
            }
            *(half8*)(xrow + q * 8) = o;
        }
    }
}

// ---------------- k2: QKV GEMM  X[131072x256] @ in_w^T -> QK / VT ----------------
__global__ __launch_bounds__(256, 2)
void k2_qkv(const f16* __restrict__ X, const f16* __restrict__ win,
            const float* __restrict__ inb, f16* __restrict__ QK, f16* __restrict__ VT) {
    __shared__ __align__(16) char sm[65536];   // 2 bufs x (A 16K | B 16K)
    const int tid = threadIdx.x, lane = tid & 63, wv = tid >> 6;
    const int bid = blockIdx.x;
    const int mt = bid / 6, nb = bid % 6;
    const size_t Mbase = (size_t)mt * 128;
    const int n0 = nb * 128;
    const int wm = wv >> 1, wn = wv & 1;
    const int c = lane & 15, g = lane >> 4;
    const int r8 = lane >> 3, chv = lane & 7;

    f32x4 acc[4][4];
#pragma unroll
    for (int a = 0; a < 4; ++a)
#pragma unroll
        for (int b = 0; b < 4; ++b) acc[a][b] = f32x4{0.f, 0.f, 0.f, 0.f};

    auto stage = [&](int step, int bsel) {
        const f16* As = X + Mbase * 256 + step * 64;
        const f16* Bs = win + (size_t)n0 * 256 + step * 64;
#pragma unroll
        for (int q = 0; q < 4; ++q) {
            int ia = wv * 4 + q;
            int row = ia * 8 + r8;
            int chs = chv ^ (row & 7);
            __builtin_amdgcn_global_load_lds(
                (const __attribute__((address_space(1))) unsigned int*)(As + (size_t)row * 256 + chs * 8),
                (__attribute__((address_space(3))) unsigned int*)(sm + bsel * 32768 + ia * 1024),
                16, 0, 0);
            __builtin_amdgcn_global_load_lds(
                (const __attribute__((address_space(1))) unsigned int*)(Bs + (size_t)row * 256 + chs * 8),
                (__attribute__((address_space(3))) unsigned int*)(sm + bsel * 32768 + 16384 + ia * 1024),
                16, 0, 0);
        }
    };
    stage(0, 0);
    __syncthreads();
    for (int s = 0; s < 4; ++s) {
        int bsel = s & 1;
        if (s < 3) stage(s + 1, bsel ^ 1);
#pragma unroll
        for (int kk2 = 0; kk2 < 2; ++kk2) {
            half8 a[4], b[4];
#pragma unroll
            for (int mi = 0; mi < 4; ++mi) {
                int row = wm * 64 + mi * 16 + c;
                a[mi] = *(half8*)(sm + bsel * 32768 + row * 128 + ((kk2 * 64 + g * 16) ^ ((row & 7) << 4)));
            }
#pragma unroll
            for (int nt = 0; nt < 4; ++nt) {
                int row = wn * 64 + nt * 16 + c;
                b[nt] = *(half8*)(sm + bsel * 32768 + 16384 + row * 128 + ((kk2 * 64 + g * 16) ^ ((row & 7) << 4)));
            }
#pragma unroll
            for (int mi = 0; mi < 4; ++mi)
#pragma unroll
                for (int nt = 0; nt < 4; ++nt)
                    acc[mi][nt] = MFMA32(a[mi], b[nt], acc[mi][nt]);
        }
        __syncthreads();
    }

    const f32x4 z4 = {0.f, 0.f, 0.f, 0.f};
    half4 idf;
#pragma unroll
    for (int j = 0; j < 4; ++j) idf[j] = (f16)((g * 4 + j == c) ? 1.f : 0.f);

    if (n0 < 512) {
        // Q,K: transpose via identity mfma, store row-major QK[t][512]
#pragma unroll
        for (int mi = 0; mi < 4; ++mi)
#pragma unroll
            for (int nt = 0; nt < 4; ++nt) {
                int n = n0 + wn * 64 + nt * 16 + c;
                float bias = inb[n];
                half4 h;
#pragma unroll
                for (int r = 0; r < 4; ++r) h[r] = (f16)(acc[mi][nt][r] + bias);
                f32x4 t = MFMA16(h, idf, z4);      // C/D-as-A (=T^T) times I -> transposed tile
                half4 o;
#pragma unroll
                for (int r = 0; r < 4; ++r) o[r] = (f16)t[r];
                size_t tok = Mbase + wm * 64 + mi * 16 + c;       // col of transposed tile = m
                *(half4*)(QK + tok * 512 + (n0 + wn * 64 + nt * 16 + g * 4)) = o;
            }
    } else {
        // V: store [win][d][t] directly from C/D (rows = 4 contiguous tokens)
#pragma unroll
        for (int mi = 0; mi < 4; ++mi)
#pragma unroll
            for (int nt = 0; nt < 4; ++nt) {
                int n = n0 + wn * 64 + nt * 16 + c;
                float bias = inb[n];
                half4 h;
#pragma unroll
                for (int r = 0; r < 4; ++r) h[r] = (f16)(acc[mi][nt][r] + bias);
                int d = n - 512;
                size_t tokb = Mbase + wm * 64 + mi * 16;          // window-aligned
                size_t winI = tokb >> 4;
                *(half4*)(VT + winI * 4096 + (size_t)d * 16 + g * 4) = h;
            }
    }
}

// ---------------- k3: attention + out-proj + proj + GELU -> G[t][256] f16 ----------------
__global__ __launch_bounds__(256, 5)
void k3_attn(const f16* __restrict__ QK, const f16* __restrict__ VT,
             const f16* __restrict__ wout, const f16* __restrict__ wproj,
             const float* __restrict__ outb, const float* __restrict__ projb,
             f16* __restrict__ G) {
    __shared__ __align__(16) char sm[32768];   // 2 x 16KB weight chunks [32 n][256 d], 4-bit XOR swizzle
    const int tid = threadIdx.x, lane = tid & 63, wv = tid >> 6;
    const int c = lane & 15, g = lane >> 4;
    const size_t win = (size_t)blockIdx.x * 4 + wv;
    const f16* qrow = QK + (win * 16 + c) * 512;
    const f32x4 z4 = {0.f, 0.f, 0.f, 0.f};

    const int nl = tid >> 3, seg = tid & 7;
    const int swz = (nl & 15) << 3;            // bits 3-6: spreads 16 rows over 16 8B-slots
    auto stageW = [&](const f16* mat, int rc, int bsel) {
        const f16* src = mat + ((size_t)(rc * 32 + nl)) * 256 + seg * 32;
        char* dst = sm + bsel * 16384 + nl * 512;
#pragma unroll
        for (int i = 0; i < 4; ++i) {
            uint4 u = *(const uint4*)(src + i * 8);
            int b0 = (seg * 64 + i * 16) ^ swz;
            int b1 = (seg * 64 + i * 16 + 8) ^ swz;
            *(uint2*)(dst + b0) = make_uint2(u.x, u.y);
            *(uint2*)(dst + b1) = make_uint2(u.z, u.w);
        }
    };

    stageW(wout, 0, 0);   // chunk 0 in flight under attention

    // ---- attention, all in registers ----
    half4 of16[4][4];
#pragma unroll
    for (int hq = 0; hq < 4; ++hq) {
        half8 af0 = *(const half8*)(qrow + 256 + hq * 64 + g * 8);
        half8 af1 = *(const half8*)(qrow + 256 + hq * 64 + 32 + g * 8);
        half8 bq0 = *(const half8*)(qrow + hq * 64 + g * 8);
        half8 bq1 = *(const half8*)(qrow + hq * 64 + 32 + g * 8);
        f32x4 sacc = MFMA32(af0, bq0, z4);     // S^T[k_tok][q]
        sacc = MFMA32(af1, bq1, sacc);
        float s0 = sacc[0] * 0.125f, s1 = sacc[1] * 0.125f;
        float s2 = sacc[2] * 0.125f, s3 = sacc[3] * 0.125f;
        float mx = fmaxf(fmaxf(s0, s1), fmaxf(s2, s3));
        mx = fmaxf(mx, __shfl_xor(mx, 16));
        mx = fmaxf(mx, __shfl_xor(mx, 32));
        float p0 = __expf(s0 - mx), p1 = __expf(s1 - mx);
        float p2 = __expf(s2 - mx), p3 = __expf(s3 - mx);
        float sum = p0 + p1 + p2 + p3;
        sum += __shfl_xor(sum, 16);
        sum += __shfl_xor(sum, 32);
        float inv = 1.f / sum;
        half4 pf;
        pf[0] = (f16)(p0 * inv); pf[1] = (f16)(p1 * inv);
        pf[2] = (f16)(p2 * inv); pf[3] = (f16)(p3 * inv);
#pragma unroll
        for (int nt = 0; nt < 4; ++nt) {
            half4 vf = *(const half4*)(VT + win * 4096 + (size_t)(hq * 64 + nt * 16 + c) * 16 + g * 4);
            f32x4 o = MFMA16(vf, pf, z4);      // O^T[d][q]
            half4 oh;
#pragma unroll
            for (int r = 0; r < 4; ++r) oh[r] = (f16)o[r];
            of16[hq][nt] = oh;
        }
    }

    // ---- out-proj: OB^T[n][q] accumulated over 16 chunks of w_out rows ----
    f32x4 obacc[16];
#pragma unroll
    for (int i = 0; i < 16; ++i) obacc[i] = z4;
    __syncthreads();
#pragma unroll
    for (int ch = 0; ch < 8; ++ch) {
        if (ch < 7) stageW(wout, ch + 1, (ch + 1) & 1);
        else        stageW(wproj, 0, (ch + 1) & 1);
        int bsel = ch & 1;
#pragma unroll
        for (int ntl = 0; ntl < 2; ++ntl) {
            int nt2 = ch * 2 + ntl;
            int rowl = ntl * 16 + c;
            char* base = sm + bsel * 16384 + rowl * 512;
            int sw2 = (rowl & 15) << 3;
            f32x4 a = obacc[nt2];
#pragma unroll
            for (int hq = 0; hq < 4; ++hq)
#pragma unroll
                for (int dt = 0; dt < 4; ++dt) {
                    half4 wf = *(const half4*)(base + (((hq * 64 + dt * 16 + g * 4) * 2) ^ sw2));
                    a = MFMA16(wf, of16[hq][dt], a);
                }
            obacc[nt2] = a;
        }
        __syncthreads();
    }
    half4 obT[16];
#pragma unroll
    for (int nt = 0; nt < 16; ++nt) {
        f32x4 bv = *(const f32x4*)(outb + nt * 16 + g * 4);
        half4 h;
#pragma unroll
        for (int r = 0; r < 4; ++r) h[r] = (f16)(obacc[nt][r] + bv[r]);
        obT[nt] = h;
    }

    // ---- proj: Y^T[n_out][q] over 8 chunks of w_proj rows ----
    f32x4 yacc[16];
#pragma unroll
    for (int i = 0; i < 16; ++i) yacc[i] = z4;
#pragma unroll
    for (int pc = 0; pc < 8; ++pc) {
        if (pc < 7) stageW(wproj, pc + 1, (pc + 1) & 1);
        int bsel = pc & 1;
#pragma unroll
        for (int ntl = 0; ntl < 2; ++ntl) {
            int nt3 = pc * 2 + ntl;
            int rowl = ntl * 16 + c;
            char* base = sm + bsel * 16384 + rowl * 512;
            int sw2 = (rowl & 15) << 3;
            f32x4 a = yacc[nt3];
#pragma unroll
            for (int ntc = 0; ntc < 16; ++ntc) {
                half4 wf = *(const half4*)(base + (((ntc * 16 + g * 4) * 2) ^ sw2));
                a = MFMA16(wf, obT[ntc], a);
            }
            yacc[nt3] = a;
        }
        __syncthreads();
    }

    // ---- bias + exact GELU + store G ----
#pragma unroll
    for (int nt = 0; nt < 16; ++nt) {
        f32x4 bv = *(const f32x4*)(projb + nt * 16 + g * 4);
        half4 h;
#pragma unroll
        for (int r = 0; r < 4; ++r) {
            float x = yacc[nt][r] + bv[r];
            h[r] = (f16)(0.5f * x * (1.f + erff(x * 0.70710678118f)));
        }
        *(half4*)(G + (win * 16 + c) * 256 + nt * 16 + g * 4) = h;
    }
}

// ---------------- k4: residual + NCHW scatter (no LDS, float4 read/write) ----------------
__global__ __launch_bounds__(256, 4)
void k4_out(const f16* __restrict__ G, const float* __restrict__ feat, float* __restrict__ outp) {
    const int tid = threadIdx.x, lane = tid & 63, hh = tid >> 6;
    const int bid = blockIdx.x;
    const int jh = bid & 3, wi = (bid >> 2) & 31, bb = bid >> 7;
    const int h0 = wi * 4, w0 = jh * 32;
    const int wl4 = lane & 7, cg = lane >> 3;
    const int h = h0 + hh, wb = w0 + wl4 * 4;
    if (h >= 127) return;
    const bool edge = (wb + 3) >= 127;
    const size_t bbase = (size_t)bb * (256 * 127 * 127);
    const int c0 = cg * 32;

    half8 gr[4][4];   // [token e][8-ch chunk q]
#pragma unroll
    for (int e = 0; e < 4; ++e) {
        const int m = wl4 * 16 + hh * 4 + e;
        const f16* grow = G + ((size_t)bid * 128 + m) * 256 + c0;
#pragma unroll
        for (int q = 0; q < 4; ++q) gr[e][q] = *(const half8*)(grow + q * 8);
    }
    const float* fp = feat + bbase + (size_t)c0 * 16129 + (size_t)h * 127 + wb;
    float* op = outp + bbase + (size_t)c0 * 16129 + (size_t)h * 127 + wb;
    if (!edge) {
#pragma unroll 8
        for (int i = 0; i < 32; ++i) {
            f32x4 f = *(const f32x4*)(fp + (size_t)i * 16129);
            f32x4 o;
#pragma unroll
            for (int e = 0; e < 4; ++e) o[e] = f[e] + (float)gr[e][i >> 3][i & 7];
            *(f32x4*)(op + (size_t)i * 16129) = o;
        }
    } else {
#pragma unroll 8
        for (int i = 0; i < 32; ++i) {
            const float* fpi = fp + (size_t)i * 16129;
            float* opi = op + (size_t)i * 16129;
#pragma unroll
            for (int e = 0; e < 3; ++e) opi[e] = fpi[e] + (float)gr[e][i >> 3][i & 7];
        }
    }
}

extern "C" void kernel_launch(void* const* d_in, const int* in_sizes, int n_in,
                              void* d_out, int out_size, void* d_ws, size_t ws_size,
                              hipStream_t stream) {
    const float* feat   = (const float*)d_in[0];
    const float* ln_w   = (const float*)d_in[1];
    const float* ln_b   = (const float*)d_in[2];
    const float* in_w   = (const float*)d_in[3];
    const float* in_b   = (const float*)d_in[4];
    const float* out_w  = (const float*)d_in[5];
    const float* out_b  = (const float*)d_in[6];
    const float* proj_w = (const float*)d_in[7];
    const float* proj_b = (const float*)d_in[8];

    f16* W  = (f16*)d_ws;
    f16* Xb  = W + X0;
    f16* QKb = W + QK0;
    f16* VTb = W + VT0;
    f16* Gb  = Xb;   // reuse X region for G (X dead after k2)

    k0_cast<<<768, 256, 0, stream>>>(in_w, out_w, proj_w, W);
    k1_pack<<<1024, 256, 0, stream>>>(feat, ln_w, ln_b, Xb);
    k2_qkv<<<6144, 256, 0, stream>>>(Xb, W + W_IN0, in_b, QKb, VTb);
    k3_attn<<<2048, 256, 0, stream>>>(QKb, VTb, W + W_OUT0, W + W_PROJ0, out_b, proj_b, Gb);
    k4_out<<<1024, 256, 0, stream>>>(Gb, feat, (float*)d_out);
}

// Round 5
// 606.575 us; speedup vs baseline: 1.1279x; 1.1279x over previous
//
#include <hip/hip_runtime.h>

typedef _Float16 f16;
typedef __attribute__((ext_vector_type(4))) _Float16 half4;
typedef __attribute__((ext_vector_type(8))) _Float16 half8;
typedef __attribute__((ext_vector_type(4))) float f32x4;
typedef unsigned short u16;

#define MFMA32(a,b,c) __builtin_amdgcn_mfma_f32_16x16x32_f16(a,b,c,0,0,0)
#define MFMA16(a,b,c) __builtin_amdgcn_mfma_f32_16x16x16f16(a,b,c,0,0,0)

// ws layout (f16 element offsets)
#define W_IN0   0
#define W_OUT0  196608
#define W_PROJ0 262144
#define X0      327680
#define QK0     33882112ull
#define VT0     100990976ull

// ---------------- k0: cast weights to f16 ----------------
__global__ void k0_cast(const float* __restrict__ iw, const float* __restrict__ ow,
                        const float* __restrict__ pw, f16* __restrict__ W) {
    int i = blockIdx.x * 256 + threadIdx.x;
    if (i < 196608) W[W_IN0 + i] = (f16)iw[i];
    if (i < 65536) {
        W[W_OUT0 + i]  = (f16)ow[i];
        W[W_PROJ0 + i] = (f16)pw[i];
    }
}

// ---------------- k1: NCHW gather + LayerNorm -> X[t][256] f16 (no LDS, float4 loads) ----------------
__global__ __launch_bounds__(256, 4)
void k1_pack(const float* __restrict__ feat, const float* __restrict__ lnw,
             const float* __restrict__ lnb, f16* __restrict__ X) {
    const int tid = threadIdx.x, lane = tid & 63, hh = tid >> 6;
    const int bid = blockIdx.x;
    const int jh = bid & 3, wi = (bid >> 2) & 31, bb = bid >> 7;
    const int h0 = wi * 4, w0 = jh * 32;
    const int wl4 = lane & 7, cg = lane >> 3;
    const int h = h0 + hh, wb = w0 + wl4 * 4;
    const bool hok = (h < 127);
    const bool edge = (wb + 3) >= 127;      // only jh==3 && wl4==7 (w=127 is pad)
    const size_t bbase = (size_t)bb * (256 * 127 * 127);
    const int c0 = cg * 32;
    const float* p0 = feat + bbase + (size_t)c0 * 16129 + (size_t)h * 127 + wb;

    half4 arr[32];                           // [ch within group][token e], f16 pre-LN
    float ss[4] = {0.f, 0.f, 0.f, 0.f}, qq[4] = {0.f, 0.f, 0.f, 0.f};
    if (hok && !edge) {
#pragma unroll 8
        for (int i = 0; i < 32; ++i) {
            f32x4 v = *(const f32x4*)(p0 + (size_t)i * 16129);
            half4 hv;
#pragma unroll
            for (int e = 0; e < 4; ++e) { ss[e] += v[e]; qq[e] += v[e] * v[e]; hv[e] = (f16)v[e]; }
            arr[i] = hv;
        }
    } else if (hok) {
#pragma unroll 8
        for (int i = 0; i < 32; ++i) {
            const float* pi = p0 + (size_t)i * 16129;
            half4 hv;
#pragma unroll
            for (int e = 0; e < 3; ++e) { float v = pi[e]; ss[e] += v; qq[e] += v * v; hv[e] = (f16)v; }
            hv[3] = (f16)0.f;
            arr[i] = hv;
        }
    } else {
#pragma unroll
        for (int i = 0; i < 32; ++i) {
            half4 hv; hv[0] = hv[1] = hv[2] = hv[3] = (f16)0.f; arr[i] = hv;
        }
    }
#pragma unroll
    for (int e = 0; e < 4; ++e) {
        ss[e] += __shfl_xor(ss[e], 8);  qq[e] += __shfl_xor(qq[e], 8);
        ss[e] += __shfl_xor(ss[e], 16); qq[e] += __shfl_xor(qq[e], 16);
        ss[e] += __shfl_xor(ss[e], 32); qq[e] += __shfl_xor(qq[e], 32);
    }
    float mu[4], rs[4];
#pragma unroll
    for (int e = 0; e < 4; ++e) {
        mu[e] = ss[e] * (1.f / 256.f);
        rs[e] = rsqrtf(qq[e] * (1.f / 256.f) - mu[e] * mu[e] + 1e-5f);
    }
#pragma unroll
    for (int q = 0; q < 4; ++q) {
        f32x4 lw0 = *(const f32x4*)(lnw + c0 + q * 8);
        f32x4 lw1 = *(const f32x4*)(lnw + c0 + q * 8 + 4);
        f32x4 lb0 = *(const f32x4*)(lnb + c0 + q * 8);
        f32x4 lb1 = *(const f32x4*)(lnb + c0 + q * 8 + 4);
#pragma unroll
        for (int e = 0; e < 4; ++e) {
            const int m = wl4 * 16 + hh * 4 + e;
            f16* xrow = X + ((size_t)bid * 128 + m) * 256 + c0;
            half8 o;
#pragma unroll
            for (int j = 0; j < 4; ++j) {
                o[j]     = (f16)(((float)arr[q * 8 + j][e]     - mu[e]) * rs[e] * lw0[j] + lb0[j]);
                o[j + 4] = (f16)(((float)arr[q * 8 + j + 4][e] - mu[e]) * rs[e] * lw1[j] + lb1[j]);
            }
            *(half8*)(xrow + q * 8) = o;
        }
    }
}

// ---------------- k2: QKV GEMM  X[131072x256] @ in_w^T -> QK / VT ----------------
__global__ __launch_bounds__(256, 2)
void k2_qkv(const f16* __restrict__ X, const f16* __restrict__ win,
            const float* __restrict__ inb, f16* __restrict__ QK, f16* __restrict__ VT) {
    __shared__ __align__(16) char sm[65536];   // 2 bufs x (A 16K | B 16K)
    const int tid = threadIdx.x, lane = tid & 63, wv = tid >> 6;
    // XCD-aware swizzle (T1): consecutive logical bids (same A-tile) land on one XCD.
    const int nwg = gridDim.x;                 // 6144, divisible by 8
    const int bid = (blockIdx.x & 7) * (nwg >> 3) + (blockIdx.x >> 3);
    const int mt = bid / 6, nb = bid % 6;
    const size_t Mbase = (size_t)mt * 128;
    const int n0 = nb * 128;
    const int wm = wv >> 1, wn = wv & 1;
    const int c = lane & 15, g = lane >> 4;
    const int r8 = lane >> 3, chv = lane & 7;

    f32x4 acc[4][4];
#pragma unroll
    for (int a = 0; a < 4; ++a)
#pragma unroll
        for (int b = 0; b < 4; ++b) acc[a][b] = f32x4{0.f, 0.f, 0.f, 0.f};

    auto stage = [&](int step, int bsel) {
        const f16* As = X + Mbase * 256 + step * 64;
        const f16* Bs = win + (size_t)n0 * 256 + step * 64;
#pragma unroll
        for (int q = 0; q < 4; ++q) {
            int ia = wv * 4 + q;
            int row = ia * 8 + r8;
            int chs = chv ^ (row & 7);
            __builtin_amdgcn_global_load_lds(
                (const __attribute__((address_space(1))) unsigned int*)(As + (size_t)row * 256 + chs * 8),
                (__attribute__((address_space(3))) unsigned int*)(sm + bsel * 32768 + ia * 1024),
                16, 0, 0);
            __builtin_amdgcn_global_load_lds(
                (const __attribute__((address_space(1))) unsigned int*)(Bs + (size_t)row * 256 + chs * 8),
                (__attribute__((address_space(3))) unsigned int*)(sm + bsel * 32768 + 16384 + ia * 1024),
                16, 0, 0);
        }
    };
    stage(0, 0);
    __syncthreads();
    for (int s = 0; s < 4; ++s) {
        int bsel = s & 1;
        if (s < 3) stage(s + 1, bsel ^ 1);
#pragma unroll
        for (int kk2 = 0; kk2 < 2; ++kk2) {
            half8 a[4], b[4];
#pragma unroll
            for (int mi = 0; mi < 4; ++mi) {
                int row = wm * 64 + mi * 16 + c;
                a[mi] = *(half8*)(sm + bsel * 32768 + row * 128 + ((kk2 * 64 + g * 16) ^ ((row & 7) << 4)));
            }
#pragma unroll
            for (int nt = 0; nt < 4; ++nt) {
                int row = wn * 64 + nt * 16 + c;
                b[nt] = *(half8*)(sm + bsel * 32768 + 16384 + row * 128 + ((kk2 * 64 + g * 16) ^ ((row & 7) << 4)));
            }
#pragma unroll
            for (int mi = 0; mi < 4; ++mi)
#pragma unroll
                for (int nt = 0; nt < 4; ++nt)
                    acc[mi][nt] = MFMA32(a[mi], b[nt], acc[mi][nt]);
        }
        __syncthreads();
    }

    const f32x4 z4 = {0.f, 0.f, 0.f, 0.f};
    half4 idf;
#pragma unroll
    for (int j = 0; j < 4; ++j) idf[j] = (f16)((g * 4 + j == c) ? 1.f : 0.f);

    if (n0 < 512) {
        // Q,K: transpose via identity mfma, store row-major QK[t][512]
#pragma unroll
        for (int mi = 0; mi < 4; ++mi)
#pragma unroll
            for (int nt = 0; nt < 4; ++nt) {
                int n = n0 + wn * 64 + nt * 16 + c;
                float bias = inb[n];
                half4 h;
#pragma unroll
                for (int r = 0; r < 4; ++r) h[r] = (f16)(acc[mi][nt][r] + bias);
                f32x4 t = MFMA16(h, idf, z4);      // C/D-as-A (=T^T) times I -> transposed tile
                half4 o;
#pragma unroll
                for (int r = 0; r < 4; ++r) o[r] = (f16)t[r];
                size_t tok = Mbase + wm * 64 + mi * 16 + c;       // col of transposed tile = m
                *(half4*)(QK + tok * 512 + (n0 + wn * 64 + nt * 16 + g * 4)) = o;
            }
    } else {
        // V: store [win][d][t] directly from C/D (rows = 4 contiguous tokens)
#pragma unroll
        for (int mi = 0; mi < 4; ++mi)
#pragma unroll
            for (int nt = 0; nt < 4; ++nt) {
                int n = n0 + wn * 64 + nt * 16 + c;
                float bias = inb[n];
                half4 h;
#pragma unroll
                for (int r = 0; r < 4; ++r) h[r] = (f16)(acc[mi][nt][r] + bias);
                int d = n - 512;
                size_t tokb = Mbase + wm * 64 + mi * 16;          // window-aligned
                size_t winI = tokb >> 4;
                *(half4*)(VT + winI * 4096 + (size_t)d * 16 + g * 4) = h;
            }
    }
}

// ---------------- k3: attention + out-proj + proj + GELU -> G[t][256] f16 ----------------
// launch_bounds(256,4): cap 128 VGPR >= natural ~84 -> NO spill (the (256,5) cap of ~102
// forced 48 VGPR + 900MB scratch traffic in round 4).
__global__ __launch_bounds__(256, 4)
void k3_attn(const f16* __restrict__ QK, const f16* __restrict__ VT,
             const f16* __restrict__ wout, const f16* __restrict__ wproj,
             const float* __restrict__ outb, const float* __restrict__ projb,
             f16* __restrict__ G) {
    __shared__ __align__(16) char sm[32768];   // 2 x 16KB weight chunks [32 n][256 d], 4-bit XOR swizzle
    const int tid = threadIdx.x, lane = tid & 63, wv = tid >> 6;
    const int c = lane & 15, g = lane >> 4;
    const size_t win = (size_t)blockIdx.x * 4 + wv;
    const f16* qrow = QK + (win * 16 + c) * 512;
    const f32x4 z4 = {0.f, 0.f, 0.f, 0.f};

    const int nl = tid >> 3, seg = tid & 7;
    const int swz = (nl & 15) << 3;            // bits 3-6: spreads 16 rows over 16 8B-slots
    auto stageW = [&](const f16* mat, int rc, int bsel) {
        const f16* src = mat + ((size_t)(rc * 32 + nl)) * 256 + seg * 32;
        char* dst = sm + bsel * 16384 + nl * 512;
#pragma unroll
        for (int i = 0; i < 4; ++i) {
            uint4 u = *(const uint4*)(src + i * 8);
            int b0 = (seg * 64 + i * 16) ^ swz;
            int b1 = (seg * 64 + i * 16 + 8) ^ swz;
            *(uint2*)(dst + b0) = make_uint2(u.x, u.y);
            *(uint2*)(dst + b1) = make_uint2(u.z, u.w);
        }
    };

    stageW(wout, 0, 0);   // chunk 0 in flight under attention

    // ---- attention, all in registers ----
    half4 of16[4][4];
#pragma unroll
    for (int hq = 0; hq < 4; ++hq) {
        half8 af0 = *(const half8*)(qrow + 256 + hq * 64 + g * 8);
        half8 af1 = *(const half8*)(qrow + 256 + hq * 64 + 32 + g * 8);
        half8 bq0 = *(const half8*)(qrow + hq * 64 + g * 8);
        half8 bq1 = *(const half8*)(qrow + hq * 64 + 32 + g * 8);
        f32x4 sacc = MFMA32(af0, bq0, z4);     // S^T[k_tok][q]
        sacc = MFMA32(af1, bq1, sacc);
        float s0 = sacc[0] * 0.125f, s1 = sacc[1] * 0.125f;
        float s2 = sacc[2] * 0.125f, s3 = sacc[3] * 0.125f;
        float mx = fmaxf(fmaxf(s0, s1), fmaxf(s2, s3));
        mx = fmaxf(mx, __shfl_xor(mx, 16));
        mx = fmaxf(mx, __shfl_xor(mx, 32));
        float p0 = __expf(s0 - mx), p1 = __expf(s1 - mx);
        float p2 = __expf(s2 - mx), p3 = __expf(s3 - mx);
        float sum = p0 + p1 + p2 + p3;
        sum += __shfl_xor(sum, 16);
        sum += __shfl_xor(sum, 32);
        float inv = 1.f / sum;
        half4 pf;
        pf[0] = (f16)(p0 * inv); pf[1] = (f16)(p1 * inv);
        pf[2] = (f16)(p2 * inv); pf[3] = (f16)(p3 * inv);
#pragma unroll
        for (int nt = 0; nt < 4; ++nt) {
            half4 vf = *(const half4*)(VT + win * 4096 + (size_t)(hq * 64 + nt * 16 + c) * 16 + g * 4);
            f32x4 o = MFMA16(vf, pf, z4);      // O^T[d][q]
            half4 oh;
#pragma unroll
            for (int r = 0; r < 4; ++r) oh[r] = (f16)o[r];
            of16[hq][nt] = oh;
        }
    }

    // ---- out-proj: OB^T[n][q] accumulated over 16 chunks of w_out rows ----
    f32x4 obacc[16];
#pragma unroll
    for (int i = 0; i < 16; ++i) obacc[i] = z4;
    __syncthreads();
#pragma unroll
    for (int ch = 0; ch < 8; ++ch) {
        if (ch < 7) stageW(wout, ch + 1, (ch + 1) & 1);
        else        stageW(wproj, 0, (ch + 1) & 1);
        int bsel = ch & 1;
#pragma unroll
        for (int ntl = 0; ntl < 2; ++ntl) {
            int nt2 = ch * 2 + ntl;
            int rowl = ntl * 16 + c;
            char* base = sm + bsel * 16384 + rowl * 512;
            int sw2 = (rowl & 15) << 3;
            f32x4 a = obacc[nt2];
#pragma unroll
            for (int hq = 0; hq < 4; ++hq)
#pragma unroll
                for (int dt = 0; dt < 4; ++dt) {
                    half4 wf = *(const half4*)(base + (((hq * 64 + dt * 16 + g * 4) * 2) ^ sw2));
                    a = MFMA16(wf, of16[hq][dt], a);
                }
            obacc[nt2] = a;
        }
        __syncthreads();
    }
    half4 obT[16];
#pragma unroll
    for (int nt = 0; nt < 16; ++nt) {
        f32x4 bv = *(const f32x4*)(outb + nt * 16 + g * 4);
        half4 h;
#pragma unroll
        for (int r = 0; r < 4; ++r) h[r] = (f16)(obacc[nt][r] + bv[r]);
        obT[nt] = h;
    }

    // ---- proj: Y^T[n_out][q] over 8 chunks of w_proj rows ----
    f32x4 yacc[16];
#pragma unroll
    for (int i = 0; i < 16; ++i) yacc[i] = z4;
#pragma unroll
    for (int pc = 0; pc < 8; ++pc) {
        if (pc < 7) stageW(wproj, pc + 1, (pc + 1) & 1);
        int bsel = pc & 1;
#pragma unroll
        for (int ntl = 0; ntl < 2; ++ntl) {
            int nt3 = pc * 2 + ntl;
            int rowl = ntl * 16 + c;
            char* base = sm + bsel * 16384 + rowl * 512;
            int sw2 = (rowl & 15) << 3;
            f32x4 a = yacc[nt3];
#pragma unroll
            for (int ntc = 0; ntc < 16; ++ntc) {
                half4 wf = *(const half4*)(base + (((ntc * 16 + g * 4) * 2) ^ sw2));
                a = MFMA16(wf, obT[ntc], a);
            }
            yacc[nt3] = a;
        }
        __syncthreads();
    }

    // ---- bias + exact GELU + store G ----
#pragma unroll
    for (int nt = 0; nt < 16; ++nt) {
        f32x4 bv = *(const f32x4*)(projb + nt * 16 + g * 4);
        half4 h;
#pragma unroll
        for (int r = 0; r < 4; ++r) {
            float x = yacc[nt][r] + bv[r];
            h[r] = (f16)(0.5f * x * (1.f + erff(x * 0.70710678118f)));
        }
        *(half4*)(G + (win * 16 + c) * 256 + nt * 16 + g * 4) = h;
    }
}

// ---------------- k4: residual + NCHW scatter (no LDS, float4 read/write) ----------------
__global__ __launch_bounds__(256, 4)
void k4_out(const f16* __restrict__ G, const float* __restrict__ feat, float* __restrict__ outp) {
    const int tid = threadIdx.x, lane = tid & 63, hh = tid >> 6;
    const int bid = blockIdx.x;
    const int jh = bid & 3, wi = (bid >> 2) & 31, bb = bid >> 7;
    const int h0 = wi * 4, w0 = jh * 32;
    const int wl4 = lane & 7, cg = lane >> 3;
    const int h = h0 + hh, wb = w0 + wl4 * 4;
    if (h >= 127) return;
    const bool edge = (wb + 3) >= 127;
    const size_t bbase = (size_t)bb * (256 * 127 * 127);
    const int c0 = cg * 32;

    half8 gr[4][4];   // [token e][8-ch chunk q]
#pragma unroll
    for (int e = 0; e < 4; ++e) {
        const int m = wl4 * 16 + hh * 4 + e;
        const f16* grow = G + ((size_t)bid * 128 + m) * 256 + c0;
#pragma unroll
        for (int q = 0; q < 4; ++q) gr[e][q] = *(const half8*)(grow + q * 8);
    }
    const float* fp = feat + bbase + (size_t)c0 * 16129 + (size_t)h * 127 + wb;
    float* op = outp + bbase + (size_t)c0 * 16129 + (size_t)h * 127 + wb;
    if (!edge) {
#pragma unroll 8
        for (int i = 0; i < 32; ++i) {
            f32x4 f = *(const f32x4*)(fp + (size_t)i * 16129);
            f32x4 o;
#pragma unroll
            for (int e = 0; e < 4; ++e) o[e] = f[e] + (float)gr[e][i >> 3][i & 7];
            *(f32x4*)(op + (size_t)i * 16129) = o;
        }
    } else {
#pragma unroll 8
        for (int i = 0; i < 32; ++i) {
            const float* fpi = fp + (size_t)i * 16129;
            float* opi = op + (size_t)i * 16129;
#pragma unroll
            for (int e = 0; e < 3; ++e) opi[e] = fpi[e] + (float)gr[e][i >> 3][i & 7];
        }
    }
}

extern "C" void kernel_launch(void* const* d_in, const int* in_sizes, int n_in,
                              void* d_out, int out_size, void* d_ws, size_t ws_size,
                              hipStream_t stream) {
    const float* feat   = (const float*)d_in[0];
    const float* ln_w   = (const float*)d_in[1];
    const float* ln_b   = (const float*)d_in[2];
    const float* in_w   = (const float*)d_in[3];
    const float* in_b   = (const float*)d_in[4];
    const float* out_w  = (const float*)d_in[5];
    const float* out_b  = (const float*)d_in[6];
    const float* proj_w = (const float*)d_in[7];
    const float* proj_b = (const float*)d_in[8];

    f16* W  = (f16*)d_ws;
    f16* Xb  = W + X0;
    f16* QKb = W + QK0;
    f16* VTb = W + VT0;
    f16* Gb  = Xb;   // reuse X region for G (X dead after k2)

    k0_cast<<<768, 256, 0, stream>>>(in_w, out_w, proj_w, W);
    k1_pack<<<1024, 256, 0, stream>>>(feat, ln_w, ln_b, Xb);
    k2_qkv<<<6144, 256, 0, stream>>>(Xb, W + W_IN0, in_b, QKb, VTb);
    k3_attn<<<2048, 256, 0, stream>>>(QKb, VTb, W + W_OUT0, W + W_PROJ0, out_b, proj_b, Gb);
    k4_out<<<1024, 256, 0, stream>>>(Gb, feat, (float*)d_out);
}

// Round 6
// 493.207 us; speedup vs baseline: 1.3872x; 1.2299x over previous
//
#include <hip/hip_runtime.h>

typedef _Float16 f16;
typedef __attribute__((ext_vector_type(4))) _Float16 half4;
typedef __attribute__((ext_vector_type(8))) _Float16 half8;
typedef __attribute__((ext_vector_type(4))) float f32x4;
typedef unsigned short u16;

#define MFMA32(a,b,c) __builtin_amdgcn_mfma_f32_16x16x32_f16(a,b,c,0,0,0)
#define MFMA16(a,b,c) __builtin_amdgcn_mfma_f32_16x16x16f16(a,b,c,0,0,0)

// ws layout (f16 element offsets)
#define W_IN0   0
#define W_OUT0  196608
#define W_PROJ0 262144
#define X0      327680
#define QK0     33882112ull
#define VT0     100990976ull

// ---------------- k0: cast weights to f16 ----------------
__global__ void k0_cast(const float* __restrict__ iw, const float* __restrict__ ow,
                        const float* __restrict__ pw, f16* __restrict__ W) {
    int i = blockIdx.x * 256 + threadIdx.x;
    if (i < 196608) W[W_IN0 + i] = (f16)iw[i];
    if (i < 65536) {
        W[W_OUT0 + i]  = (f16)ow[i];
        W[W_PROJ0 + i] = (f16)pw[i];
    }
}

// ---------------- k1: NCHW gather + LayerNorm -> X[t][256] f16 (no LDS, float4 loads) ----------------
__global__ __launch_bounds__(256, 4)
void k1_pack(const float* __restrict__ feat, const float* __restrict__ lnw,
             const float* __restrict__ lnb, f16* __restrict__ X) {
    const int tid = threadIdx.x, lane = tid & 63, hh = tid >> 6;
    const int bid = blockIdx.x;
    const int jh = bid & 3, wi = (bid >> 2) & 31, bb = bid >> 7;
    const int h0 = wi * 4, w0 = jh * 32;
    const int wl4 = lane & 7, cg = lane >> 3;
    const int h = h0 + hh, wb = w0 + wl4 * 4;
    const bool hok = (h < 127);
    const bool edge = (wb + 3) >= 127;      // only jh==3 && wl4==7 (w=127 is pad)
    const size_t bbase = (size_t)bb * (256 * 127 * 127);
    const int c0 = cg * 32;
    const float* p0 = feat + bbase + (size_t)c0 * 16129 + (size_t)h * 127 + wb;

    half4 arr[32];                           // [ch within group][token e], f16 pre-LN
    float ss[4] = {0.f, 0.f, 0.f, 0.f}, qq[4] = {0.f, 0.f, 0.f, 0.f};
    if (hok && !edge) {
#pragma unroll 8
        for (int i = 0; i < 32; ++i) {
            f32x4 v = *(const f32x4*)(p0 + (size_t)i * 16129);
            half4 hv;
#pragma unroll
            for (int e = 0; e < 4; ++e) { ss[e] += v[e]; qq[e] += v[e] * v[e]; hv[e] = (f16)v[e]; }
            arr[i] = hv;
        }
    } else if (hok) {
#pragma unroll 8
        for (int i = 0; i < 32; ++i) {
            const float* pi = p0 + (size_t)i * 16129;
            half4 hv;
#pragma unroll
            for (int e = 0; e < 3; ++e) { float v = pi[e]; ss[e] += v; qq[e] += v * v; hv[e] = (f16)v; }
            hv[3] = (f16)0.f;
            arr[i] = hv;
        }
    } else {
#pragma unroll
        for (int i = 0; i < 32; ++i) {
            half4 hv; hv[0] = hv[1] = hv[2] = hv[3] = (f16)0.f; arr[i] = hv;
        }
    }
#pragma unroll
    for (int e = 0; e < 4; ++e) {
        ss[e] += __shfl_xor(ss[e], 8);  qq[e] += __shfl_xor(qq[e], 8);
        ss[e] += __shfl_xor(ss[e], 16); qq[e] += __shfl_xor(qq[e], 16);
        ss[e] += __shfl_xor(ss[e], 32); qq[e] += __shfl_xor(qq[e], 32);
    }
    float mu[4], rs[4];
#pragma unroll
    for (int e = 0; e < 4; ++e) {
        mu[e] = ss[e] * (1.f / 256.f);
        rs[e] = rsqrtf(qq[e] * (1.f / 256.f) - mu[e] * mu[e] + 1e-5f);
    }
#pragma unroll
    for (int q = 0; q < 4; ++q) {
        f32x4 lw0 = *(const f32x4*)(lnw + c0 + q * 8);
        f32x4 lw1 = *(const f32x4*)(lnw + c0 + q * 8 + 4);
        f32x4 lb0 = *(const f32x4*)(lnb + c0 + q * 8);
        f32x4 lb1 = *(const f32x4*)(lnb + c0 + q * 8 + 4);
#pragma unroll
        for (int e = 0; e < 4; ++e) {
            const int m = wl4 * 16 + hh * 4 + e;
            f16* xrow = X + ((size_t)bid * 128 + m) * 256 + c0;
            half8 o;
#pragma unroll
            for (int j = 0; j < 4; ++j) {
                o[j]     = (f16)(((float)arr[q * 8 + j][e]     - mu[e]) * rs[e] * lw0[j] + lb0[j]);
                o[j + 4] = (f16)(((float)arr[q * 8 + j + 4][e] - mu[e]) * rs[e] * lw1[j] + lb1[j]);
            }
            *(half8*)(xrow + q * 8) = o;
        }
    }
}

// ---------------- k2: QKV GEMM  X[131072x256] @ in_w^T -> QK / VT ----------------
__global__ __launch_bounds__(256, 2)
void k2_qkv(const f16* __restrict__ X, const f16* __restrict__ win,
            const float* __restrict__ inb, f16* __restrict__ QK, f16* __restrict__ VT) {
    __shared__ __align__(16) char sm[65536];   // 2 bufs x (A 16K | B 16K)
    const int tid = threadIdx.x, lane = tid & 63, wv = tid >> 6;
    // XCD-aware swizzle (T1): consecutive logical bids (same A-tile) land on one XCD.
    const int nwg = gridDim.x;                 // 6144, divisible by 8
    const int bid = (blockIdx.x & 7) * (nwg >> 3) + (blockIdx.x >> 3);
    const int mt = bid / 6, nb = bid % 6;
    const size_t Mbase = (size_t)mt * 128;
    const int n0 = nb * 128;
    const int wm = wv >> 1, wn = wv & 1;
    const int c = lane & 15, g = lane >> 4;
    const int r8 = lane >> 3, chv = lane & 7;

    f32x4 acc[4][4];
#pragma unroll
    for (int a = 0; a < 4; ++a)
#pragma unroll
        for (int b = 0; b < 4; ++b) acc[a][b] = f32x4{0.f, 0.f, 0.f, 0.f};

    auto stage = [&](int step, int bsel) {
        const f16* As = X + Mbase * 256 + step * 64;
        const f16* Bs = win + (size_t)n0 * 256 + step * 64;
#pragma unroll
        for (int q = 0; q < 4; ++q) {
            int ia = wv * 4 + q;
            int row = ia * 8 + r8;
            int chs = chv ^ (row & 7);
            __builtin_amdgcn_global_load_lds(
                (const __attribute__((address_space(1))) unsigned int*)(As + (size_t)row * 256 + chs * 8),
                (__attribute__((address_space(3))) unsigned int*)(sm + bsel * 32768 + ia * 1024),
                16, 0, 0);
            __builtin_amdgcn_global_load_lds(
                (const __attribute__((address_space(1))) unsigned int*)(Bs + (size_t)row * 256 + chs * 8),
                (__attribute__((address_space(3))) unsigned int*)(sm + bsel * 32768 + 16384 + ia * 1024),
                16, 0, 0);
        }
    };
    stage(0, 0);
    __syncthreads();
    for (int s = 0; s < 4; ++s) {
        int bsel = s & 1;
        if (s < 3) stage(s + 1, bsel ^ 1);
#pragma unroll
        for (int kk2 = 0; kk2 < 2; ++kk2) {
            half8 a[4], b[4];
#pragma unroll
            for (int mi = 0; mi < 4; ++mi) {
                int row = wm * 64 + mi * 16 + c;
                a[mi] = *(half8*)(sm + bsel * 32768 + row * 128 + ((kk2 * 64 + g * 16) ^ ((row & 7) << 4)));
            }
#pragma unroll
            for (int nt = 0; nt < 4; ++nt) {
                int row = wn * 64 + nt * 16 + c;
                b[nt] = *(half8*)(sm + bsel * 32768 + 16384 + row * 128 + ((kk2 * 64 + g * 16) ^ ((row & 7) << 4)));
            }
#pragma unroll
            for (int mi = 0; mi < 4; ++mi)
#pragma unroll
                for (int nt = 0; nt < 4; ++nt)
                    acc[mi][nt] = MFMA32(a[mi], b[nt], acc[mi][nt]);
        }
        __syncthreads();
    }

    const f32x4 z4 = {0.f, 0.f, 0.f, 0.f};
    half4 idf;
#pragma unroll
    for (int j = 0; j < 4; ++j) idf[j] = (f16)((g * 4 + j == c) ? 1.f : 0.f);

    if (n0 < 512) {
        // Q,K: transpose via identity mfma, store row-major QK[t][512]
#pragma unroll
        for (int mi = 0; mi < 4; ++mi)
#pragma unroll
            for (int nt = 0; nt < 4; ++nt) {
                int n = n0 + wn * 64 + nt * 16 + c;
                float bias = inb[n];
                half4 h;
#pragma unroll
                for (int r = 0; r < 4; ++r) h[r] = (f16)(acc[mi][nt][r] + bias);
                f32x4 t = MFMA16(h, idf, z4);      // C/D-as-A (=T^T) times I -> transposed tile
                half4 o;
#pragma unroll
                for (int r = 0; r < 4; ++r) o[r] = (f16)t[r];
                size_t tok = Mbase + wm * 64 + mi * 16 + c;       // col of transposed tile = m
                *(half4*)(QK + tok * 512 + (n0 + wn * 64 + nt * 16 + g * 4)) = o;
            }
    } else {
        // V: store [win][d][t] directly from C/D (rows = 4 contiguous tokens)
#pragma unroll
        for (int mi = 0; mi < 4; ++mi)
#pragma unroll
            for (int nt = 0; nt < 4; ++nt) {
                int n = n0 + wn * 64 + nt * 16 + c;
                float bias = inb[n];
                half4 h;
#pragma unroll
                for (int r = 0; r < 4; ++r) h[r] = (f16)(acc[mi][nt][r] + bias);
                int d = n - 512;
                size_t tokb = Mbase + wm * 64 + mi * 16;          // window-aligned
                size_t winI = tokb >> 4;
                *(half4*)(VT + winI * 4096 + (size_t)d * 16 + g * 4) = h;
            }
    }
}

// ---------------- k3: attention + out-proj + proj + GELU -> G[t][256] f16 ----------------
// launch_bounds(256,3): budget 170 regs/wave; gfx950 splits unified file ~half arch / half
// accum for MFMA kernels -> arch ~84 = natural usage, NO spill. (256,4) gave arch 64 ->
// spill (R5: WRITE 386MB); (256,5) gave 48 -> heavy spill (R4). Do not lower the budget.
__global__ __launch_bounds__(256, 3)
void k3_attn(const f16* __restrict__ QK, const f16* __restrict__ VT,
             const f16* __restrict__ wout, const f16* __restrict__ wproj,
             const float* __restrict__ outb, const float* __restrict__ projb,
             f16* __restrict__ G) {
    __shared__ __align__(16) char sm[32768];   // 2 x 16KB weight chunks [32 n][256 d], 4-bit XOR swizzle
    const int tid = threadIdx.x, lane = tid & 63, wv = tid >> 6;
    const int c = lane & 15, g = lane >> 4;
    const size_t win = (size_t)blockIdx.x * 4 + wv;
    const f16* qrow = QK + (win * 16 + c) * 512;
    const f32x4 z4 = {0.f, 0.f, 0.f, 0.f};

    const int nl = tid >> 3, seg = tid & 7;
    const int swz = (nl & 15) << 3;            // bits 3-6: spreads 16 rows over 16 8B-slots
    auto stageW = [&](const f16* mat, int rc, int bsel) {
        const f16* src = mat + ((size_t)(rc * 32 + nl)) * 256 + seg * 32;
        char* dst = sm + bsel * 16384 + nl * 512;
#pragma unroll
        for (int i = 0; i < 4; ++i) {
            uint4 u = *(const uint4*)(src + i * 8);
            int b0 = (seg * 64 + i * 16) ^ swz;
            int b1 = (seg * 64 + i * 16 + 8) ^ swz;
            *(uint2*)(dst + b0) = make_uint2(u.x, u.y);
            *(uint2*)(dst + b1) = make_uint2(u.z, u.w);
        }
    };

    stageW(wout, 0, 0);   // chunk 0 in flight under attention

    // ---- attention, all in registers ----
    half4 of16[4][4];
#pragma unroll
    for (int hq = 0; hq < 4; ++hq) {
        half8 af0 = *(const half8*)(qrow + 256 + hq * 64 + g * 8);
        half8 af1 = *(const half8*)(qrow + 256 + hq * 64 + 32 + g * 8);
        half8 bq0 = *(const half8*)(qrow + hq * 64 + g * 8);
        half8 bq1 = *(const half8*)(qrow + hq * 64 + 32 + g * 8);
        f32x4 sacc = MFMA32(af0, bq0, z4);     // S^T[k_tok][q]
        sacc = MFMA32(af1, bq1, sacc);
        float s0 = sacc[0] * 0.125f, s1 = sacc[1] * 0.125f;
        float s2 = sacc[2] * 0.125f, s3 = sacc[3] * 0.125f;
        float mx = fmaxf(fmaxf(s0, s1), fmaxf(s2, s3));
        mx = fmaxf(mx, __shfl_xor(mx, 16));
        mx = fmaxf(mx, __shfl_xor(mx, 32));
        float p0 = __expf(s0 - mx), p1 = __expf(s1 - mx);
        float p2 = __expf(s2 - mx), p3 = __expf(s3 - mx);
        float sum = p0 + p1 + p2 + p3;
        sum += __shfl_xor(sum, 16);
        sum += __shfl_xor(sum, 32);
        float inv = 1.f / sum;
        half4 pf;
        pf[0] = (f16)(p0 * inv); pf[1] = (f16)(p1 * inv);
        pf[2] = (f16)(p2 * inv); pf[3] = (f16)(p3 * inv);
#pragma unroll
        for (int nt = 0; nt < 4; ++nt) {
            half4 vf = *(const half4*)(VT + win * 4096 + (size_t)(hq * 64 + nt * 16 + c) * 16 + g * 4);
            f32x4 o = MFMA16(vf, pf, z4);      // O^T[d][q]
            half4 oh;
#pragma unroll
            for (int r = 0; r < 4; ++r) oh[r] = (f16)o[r];
            of16[hq][nt] = oh;
        }
    }

    // ---- out-proj: OB^T[n][q] accumulated over 16 chunks of w_out rows ----
    f32x4 obacc[16];
#pragma unroll
    for (int i = 0; i < 16; ++i) obacc[i] = z4;
    __syncthreads();
#pragma unroll
    for (int ch = 0; ch < 8; ++ch) {
        if (ch < 7) stageW(wout, ch + 1, (ch + 1) & 1);
        else        stageW(wproj, 0, (ch + 1) & 1);
        int bsel = ch & 1;
#pragma unroll
        for (int ntl = 0; ntl < 2; ++ntl) {
            int nt2 = ch * 2 + ntl;
            int rowl = ntl * 16 + c;
            char* base = sm + bsel * 16384 + rowl * 512;
            int sw2 = (rowl & 15) << 3;
            f32x4 a = obacc[nt2];
#pragma unroll
            for (int hq = 0; hq < 4; ++hq)
#pragma unroll
                for (int dt = 0; dt < 4; ++dt) {
                    half4 wf = *(const half4*)(base + (((hq * 64 + dt * 16 + g * 4) * 2) ^ sw2));
                    a = MFMA16(wf, of16[hq][dt], a);
                }
            obacc[nt2] = a;
        }
        __syncthreads();
    }
    half4 obT[16];
#pragma unroll
    for (int nt = 0; nt < 16; ++nt) {
        f32x4 bv = *(const f32x4*)(outb + nt * 16 + g * 4);
        half4 h;
#pragma unroll
        for (int r = 0; r < 4; ++r) h[r] = (f16)(obacc[nt][r] + bv[r]);
        obT[nt] = h;
    }

    // ---- proj: Y^T[n_out][q] over 8 chunks of w_proj rows ----
    f32x4 yacc[16];
#pragma unroll
    for (int i = 0; i < 16; ++i) yacc[i] = z4;
#pragma unroll
    for (int pc = 0; pc < 8; ++pc) {
        if (pc < 7) stageW(wproj, pc + 1, (pc + 1) & 1);
        int bsel = pc & 1;
#pragma unroll
        for (int ntl = 0; ntl < 2; ++ntl) {
            int nt3 = pc * 2 + ntl;
            int rowl = ntl * 16 + c;
            char* base = sm + bsel * 16384 + rowl * 512;
            int sw2 = (rowl & 15) << 3;
            f32x4 a = yacc[nt3];
#pragma unroll
            for (int ntc = 0; ntc < 16; ++ntc) {
                half4 wf = *(const half4*)(base + (((ntc * 16 + g * 4) * 2) ^ sw2));
                a = MFMA16(wf, obT[ntc], a);
            }
            yacc[nt3] = a;
        }
        __syncthreads();
    }

    // ---- bias + exact GELU + store G ----
#pragma unroll
    for (int nt = 0; nt < 16; ++nt) {
        f32x4 bv = *(const f32x4*)(projb + nt * 16 + g * 4);
        half4 h;
#pragma unroll
        for (int r = 0; r < 4; ++r) {
            float x = yacc[nt][r] + bv[r];
            h[r] = (f16)(0.5f * x * (1.f + erff(x * 0.70710678118f)));
        }
        *(half4*)(G + (win * 16 + c) * 256 + nt * 16 + g * 4) = h;
    }
}

// ---------------- k4: residual + NCHW scatter (no LDS, float4 read/write) ----------------
__global__ __launch_bounds__(256, 4)
void k4_out(const f16* __restrict__ G, const float* __restrict__ feat, float* __restrict__ outp) {
    const int tid = threadIdx.x, lane = tid & 63, hh = tid >> 6;
    const int bid = blockIdx.x;
    const int jh = bid & 3, wi = (bid >> 2) & 31, bb = bid >> 7;
    const int h0 = wi * 4, w0 = jh * 32;
    const int wl4 = lane & 7, cg = lane >> 3;
    const int h = h0 + hh, wb = w0 + wl4 * 4;
    if (h >= 127) return;
    const bool edge = (wb + 3) >= 127;
    const size_t bbase = (size_t)bb * (256 * 127 * 127);
    const int c0 = cg * 32;

    half8 gr[4][4];   // [token e][8-ch chunk q]
#pragma unroll
    for (int e = 0; e < 4; ++e) {
        const int m = wl4 * 16 + hh * 4 + e;
        const f16* grow = G + ((size_t)bid * 128 + m) * 256 + c0;
#pragma unroll
        for (int q = 0; q < 4; ++q) gr[e][q] = *(const half8*)(grow + q * 8);
    }
    const float* fp = feat + bbase + (size_t)c0 * 16129 + (size_t)h * 127 + wb;
    float* op = outp + bbase + (size_t)c0 * 16129 + (size_t)h * 127 + wb;
    if (!edge) {
#pragma unroll 8
        for (int i = 0; i < 32; ++i) {
            f32x4 f = *(const f32x4*)(fp + (size_t)i * 16129);
            f32x4 o;
#pragma unroll
            for (int e = 0; e < 4; ++e) o[e] = f[e] + (float)gr[e][i >> 3][i & 7];
            *(f32x4*)(op + (size_t)i * 16129) = o;
        }
    } else {
#pragma unroll 8
        for (int i = 0; i < 32; ++i) {
            const float* fpi = fp + (size_t)i * 16129;
            float* opi = op + (size_t)i * 16129;
#pragma unroll
            for (int e = 0; e < 3; ++e) opi[e] = fpi[e] + (float)gr[e][i >> 3][i & 7];
        }
    }
}

extern "C" void kernel_launch(void* const* d_in, const int* in_sizes, int n_in,
                              void* d_out, int out_size, void* d_ws, size_t ws_size,
                              hipStream_t stream) {
    const float* feat   = (const float*)d_in[0];
    const float* ln_w   = (const float*)d_in[1];
    const float* ln_b   = (const float*)d_in[2];
    const float* in_w   = (const float*)d_in[3];
    const float* in_b   = (const float*)d_in[4];
    const float* out_w  = (const float*)d_in[5];
    const float* out_b  = (const float*)d_in[6];
    const float* proj_w = (const float*)d_in[7];
    const float* proj_b = (const float*)d_in[8];

    f16* W  = (f16*)d_ws;
    f16* Xb  = W + X0;
    f16* QKb = W + QK0;
    f16* VTb = W + VT0;
    f16* Gb  = Xb;   // reuse X region for G (X dead after k2)

    k0_cast<<<768, 256, 0, stream>>>(in_w, out_w, proj_w, W);
    k1_pack<<<1024, 256, 0, stream>>>(feat, ln_w, ln_b, Xb);
    k2_qkv<<<6144, 256, 0, stream>>>(Xb, W + W_IN0, in_b, QKb, VTb);
    k3_attn<<<2048, 256, 0, stream>>>(QKb, VTb, W + W_OUT0, W + W_PROJ0, out_b, proj_b, Gb);
    k4_out<<<1024, 256, 0, stream>>>(Gb, feat, (float*)d_out);
}

// Round 7
// 431.599 us; speedup vs baseline: 1.5852x; 1.1427x over previous
//
#include <hip/hip_runtime.h>

typedef _Float16 f16;
typedef __attribute__((ext_vector_type(4))) _Float16 half4;
typedef __attribute__((ext_vector_type(8))) _Float16 half8;
typedef __attribute__((ext_vector_type(4))) float f32x4;
typedef unsigned short u16;

#define MFMA32(a,b,c) __builtin_amdgcn_mfma_f32_16x16x32_f16(a,b,c,0,0,0)
#define MFMA16(a,b,c) __builtin_amdgcn_mfma_f32_16x16x16f16(a,b,c,0,0,0)

// ws layout (f16 element offsets)
#define W_IN0   0
#define W_OUT0  196608
#define W_PROJ0 262144
#define X0      327680
#define QK0     33882112ull
#define VT0     100990976ull

// ---------------- k0: cast weights to f16 ----------------
__global__ void k0_cast(const float* __restrict__ iw, const float* __restrict__ ow,
                        const float* __restrict__ pw, f16* __restrict__ W) {
    int i = blockIdx.x * 256 + threadIdx.x;
    if (i < 196608) W[W_IN0 + i] = (f16)iw[i];
    if (i < 65536) {
        W[W_OUT0 + i]  = (f16)ow[i];
        W[W_PROJ0 + i] = (f16)pw[i];
    }
}

// ---------------- k1: NCHW gather + LayerNorm -> X[t][256] f16 (no LDS, float4 loads) ----------------
__global__ __launch_bounds__(256, 4)
void k1_pack(const float* __restrict__ feat, const float* __restrict__ lnw,
             const float* __restrict__ lnb, f16* __restrict__ X) {
    const int tid = threadIdx.x, lane = tid & 63, hh = tid >> 6;
    const int bid = blockIdx.x;
    const int jh = bid & 3, wi = (bid >> 2) & 31, bb = bid >> 7;
    const int h0 = wi * 4, w0 = jh * 32;
    const int wl4 = lane & 7, cg = lane >> 3;
    const int h = h0 + hh, wb = w0 + wl4 * 4;
    const bool hok = (h < 127);
    const bool edge = (wb + 3) >= 127;      // only jh==3 && wl4==7 (w=127 is pad)
    const size_t bbase = (size_t)bb * (256 * 127 * 127);
    const int c0 = cg * 32;
    const float* p0 = feat + bbase + (size_t)c0 * 16129 + (size_t)h * 127 + wb;

    half4 arr[32];                           // [ch within group][token e], f16 pre-LN
    float ss[4] = {0.f, 0.f, 0.f, 0.f}, qq[4] = {0.f, 0.f, 0.f, 0.f};
    if (hok && !edge) {
#pragma unroll 8
        for (int i = 0; i < 32; ++i) {
            f32x4 v = *(const f32x4*)(p0 + (size_t)i * 16129);
            half4 hv;
#pragma unroll
            for (int e = 0; e < 4; ++e) { ss[e] += v[e]; qq[e] += v[e] * v[e]; hv[e] = (f16)v[e]; }
            arr[i] = hv;
        }
    } else if (hok) {
#pragma unroll 8
        for (int i = 0; i < 32; ++i) {
            const float* pi = p0 + (size_t)i * 16129;
            half4 hv;
#pragma unroll
            for (int e = 0; e < 3; ++e) { float v = pi[e]; ss[e] += v; qq[e] += v * v; hv[e] = (f16)v; }
            hv[3] = (f16)0.f;
            arr[i] = hv;
        }
    } else {
#pragma unroll
        for (int i = 0; i < 32; ++i) {
            half4 hv; hv[0] = hv[1] = hv[2] = hv[3] = (f16)0.f; arr[i] = hv;
        }
    }
#pragma unroll
    for (int e = 0; e < 4; ++e) {
        ss[e] += __shfl_xor(ss[e], 8);  qq[e] += __shfl_xor(qq[e], 8);
        ss[e] += __shfl_xor(ss[e], 16); qq[e] += __shfl_xor(qq[e], 16);
        ss[e] += __shfl_xor(ss[e], 32); qq[e] += __shfl_xor(qq[e], 32);
    }
    float mu[4], rs[4];
#pragma unroll
    for (int e = 0; e < 4; ++e) {
        mu[e] = ss[e] * (1.f / 256.f);
        rs[e] = rsqrtf(qq[e] * (1.f / 256.f) - mu[e] * mu[e] + 1e-5f);
    }
#pragma unroll
    for (int q = 0; q < 4; ++q) {
        f32x4 lw0 = *(const f32x4*)(lnw + c0 + q * 8);
        f32x4 lw1 = *(const f32x4*)(lnw + c0 + q * 8 + 4);
        f32x4 lb0 = *(const f32x4*)(lnb + c0 + q * 8);
        f32x4 lb1 = *(const f32x4*)(lnb + c0 + q * 8 + 4);
#pragma unroll
        for (int e = 0; e < 4; ++e) {
            const int m = wl4 * 16 + hh * 4 + e;
            f16* xrow = X + ((size_t)bid * 128 + m) * 256 + c0;
            half8 o;
#pragma unroll
            for (int j = 0; j < 4; ++j) {
                o[j]     = (f16)(((float)arr[q * 8 + j][e]     - mu[e]) * rs[e] * lw0[j] + lb0[j]);
                o[j + 4] = (f16)(((float)arr[q * 8 + j + 4][e] - mu[e]) * rs[e] * lw1[j] + lb1[j]);
            }
            *(half8*)(xrow + q * 8) = o;
        }
    }
}

// ---------------- k2: QKV GEMM  X[131072x256] @ in_w^T -> QK / VT ----------------
__global__ __launch_bounds__(256, 2)
void k2_qkv(const f16* __restrict__ X, const f16* __restrict__ win,
            const float* __restrict__ inb, f16* __restrict__ QK, f16* __restrict__ VT) {
    __shared__ __align__(16) char sm[65536];   // 2 bufs x (A 16K | B 16K)
    const int tid = threadIdx.x, lane = tid & 63, wv = tid >> 6;
    // XCD-aware swizzle (T1): consecutive logical bids (same A-tile) land on one XCD.
    const int nwg = gridDim.x;                 // 6144, divisible by 8
    const int bid = (blockIdx.x & 7) * (nwg >> 3) + (blockIdx.x >> 3);
    const int mt = bid / 6, nb = bid % 6;
    const size_t Mbase = (size_t)mt * 128;
    const int n0 = nb * 128;
    const int wm = wv >> 1, wn = wv & 1;
    const int c = lane & 15, g = lane >> 4;
    const int r8 = lane >> 3, chv = lane & 7;

    f32x4 acc[4][4];
#pragma unroll
    for (int a = 0; a < 4; ++a)
#pragma unroll
        for (int b = 0; b < 4; ++b) acc[a][b] = f32x4{0.f, 0.f, 0.f, 0.f};

    auto stage = [&](int step, int bsel) {
        const f16* As = X + Mbase * 256 + step * 64;
        const f16* Bs = win + (size_t)n0 * 256 + step * 64;
#pragma unroll
        for (int q = 0; q < 4; ++q) {
            int ia = wv * 4 + q;
            int row = ia * 8 + r8;
            int chs = chv ^ (row & 7);
            __builtin_amdgcn_global_load_lds(
                (const __attribute__((address_space(1))) unsigned int*)(As + (size_t)row * 256 + chs * 8),
                (__attribute__((address_space(3))) unsigned int*)(sm + bsel * 32768 + ia * 1024),
                16, 0, 0);
            __builtin_amdgcn_global_load_lds(
                (const __attribute__((address_space(1))) unsigned int*)(Bs + (size_t)row * 256 + chs * 8),
                (__attribute__((address_space(3))) unsigned int*)(sm + bsel * 32768 + 16384 + ia * 1024),
                16, 0, 0);
        }
    };
    stage(0, 0);
    __syncthreads();
    for (int s = 0; s < 4; ++s) {
        int bsel = s & 1;
        if (s < 3) stage(s + 1, bsel ^ 1);
#pragma unroll
        for (int kk2 = 0; kk2 < 2; ++kk2) {
            half8 a[4], b[4];
#pragma unroll
            for (int mi = 0; mi < 4; ++mi) {
                int row = wm * 64 + mi * 16 + c;
                a[mi] = *(half8*)(sm + bsel * 32768 + row * 128 + ((kk2 * 64 + g * 16) ^ ((row & 7) << 4)));
            }
#pragma unroll
            for (int nt = 0; nt < 4; ++nt) {
                int row = wn * 64 + nt * 16 + c;
                b[nt] = *(half8*)(sm + bsel * 32768 + 16384 + row * 128 + ((kk2 * 64 + g * 16) ^ ((row & 7) << 4)));
            }
#pragma unroll
            for (int mi = 0; mi < 4; ++mi)
#pragma unroll
                for (int nt = 0; nt < 4; ++nt)
                    acc[mi][nt] = MFMA32(a[mi], b[nt], acc[mi][nt]);
        }
        __syncthreads();
    }

    const f32x4 z4 = {0.f, 0.f, 0.f, 0.f};
    half4 idf;
#pragma unroll
    for (int j = 0; j < 4; ++j) idf[j] = (f16)((g * 4 + j == c) ? 1.f : 0.f);

    if (n0 < 512) {
        // Q,K: transpose via identity mfma, store row-major QK[t][512]
#pragma unroll
        for (int mi = 0; mi < 4; ++mi)
#pragma unroll
            for (int nt = 0; nt < 4; ++nt) {
                int n = n0 + wn * 64 + nt * 16 + c;
                float bias = inb[n];
                half4 h;
#pragma unroll
                for (int r = 0; r < 4; ++r) h[r] = (f16)(acc[mi][nt][r] + bias);
                f32x4 t = MFMA16(h, idf, z4);      // C/D-as-A (=T^T) times I -> transposed tile
                half4 o;
#pragma unroll
                for (int r = 0; r < 4; ++r) o[r] = (f16)t[r];
                size_t tok = Mbase + wm * 64 + mi * 16 + c;       // col of transposed tile = m
                *(half4*)(QK + tok * 512 + (n0 + wn * 64 + nt * 16 + g * 4)) = o;
            }
    } else {
        // V: store [win][d][t] directly from C/D (rows = 4 contiguous tokens)
#pragma unroll
        for (int mi = 0; mi < 4; ++mi)
#pragma unroll
            for (int nt = 0; nt < 4; ++nt) {
                int n = n0 + wn * 64 + nt * 16 + c;
                float bias = inb[n];
                half4 h;
#pragma unroll
                for (int r = 0; r < 4; ++r) h[r] = (f16)(acc[mi][nt][r] + bias);
                int d = n - 512;
                size_t tokb = Mbase + wm * 64 + mi * 16;          // window-aligned
                size_t winI = tokb >> 4;
                *(half4*)(VT + winI * 4096 + (size_t)d * 16 + g * 4) = h;
            }
    }
}

// ---------------- k3: attention + out-proj + proj + GELU -> G[t][256] f16 ----------------
// launch_bounds(256,3): budget 170 regs/wave; gfx950 splits unified file ~half arch / half
// accum for MFMA kernels -> arch ~84 = natural usage, NO spill. (256,4) gave arch 64 ->
// spill (R5: WRITE 386MB); (256,5) gave 48 -> heavy spill (R4). Do not lower the budget.
__global__ __launch_bounds__(256, 3)
void k3_attn(const f16* __restrict__ QK, const f16* __restrict__ VT,
             const f16* __restrict__ wout, const f16* __restrict__ wproj,
             const float* __restrict__ outb, const float* __restrict__ projb,
             f16* __restrict__ G) {
    __shared__ __align__(16) char sm[32768];   // 2 x 16KB weight chunks [32 n][256 d], 4-bit XOR swizzle
    const int tid = threadIdx.x, lane = tid & 63, wv = tid >> 6;
    const int c = lane & 15, g = lane >> 4;
    const size_t win = (size_t)blockIdx.x * 4 + wv;
    const f16* qrow = QK + (win * 16 + c) * 512;
    const f32x4 z4 = {0.f, 0.f, 0.f, 0.f};

    const int nl = tid >> 3, seg = tid & 7;
    const int swz = (nl & 15) << 3;            // bits 3-6: spreads 16 rows over 16 8B-slots
    auto stageW = [&](const f16* mat, int rc, int bsel) {
        const f16* src = mat + ((size_t)(rc * 32 + nl)) * 256 + seg * 32;
        char* dst = sm + bsel * 16384 + nl * 512;
#pragma unroll
        for (int i = 0; i < 4; ++i) {
            uint4 u = *(const uint4*)(src + i * 8);
            int b0 = (seg * 64 + i * 16) ^ swz;
            int b1 = (seg * 64 + i * 16 + 8) ^ swz;
            *(uint2*)(dst + b0) = make_uint2(u.x, u.y);
            *(uint2*)(dst + b1) = make_uint2(u.z, u.w);
        }
    };

    stageW(wout, 0, 0);   // chunk 0 in flight under attention

    // ---- attention, all in registers ----
    half4 of16[4][4];
#pragma unroll
    for (int hq = 0; hq < 4; ++hq) {
        half8 af0 = *(const half8*)(qrow + 256 + hq * 64 + g * 8);
        half8 af1 = *(const half8*)(qrow + 256 + hq * 64 + 32 + g * 8);
        half8 bq0 = *(const half8*)(qrow + hq * 64 + g * 8);
        half8 bq1 = *(const half8*)(qrow + hq * 64 + 32 + g * 8);
        f32x4 sacc = MFMA32(af0, bq0, z4);     // S^T[k_tok][q]
        sacc = MFMA32(af1, bq1, sacc);
        float s0 = sacc[0] * 0.125f, s1 = sacc[1] * 0.125f;
        float s2 = sacc[2] * 0.125f, s3 = sacc[3] * 0.125f;
        float mx = fmaxf(fmaxf(s0, s1), fmaxf(s2, s3));
        mx = fmaxf(mx, __shfl_xor(mx, 16));
        mx = fmaxf(mx, __shfl_xor(mx, 32));
        float p0 = __expf(s0 - mx), p1 = __expf(s1 - mx);
        float p2 = __expf(s2 - mx), p3 = __expf(s3 - mx);
        float sum = p0 + p1 + p2 + p3;
        sum += __shfl_xor(sum, 16);
        sum += __shfl_xor(sum, 32);
        float inv = 1.f / sum;
        half4 pf;
        pf[0] = (f16)(p0 * inv); pf[1] = (f16)(p1 * inv);
        pf[2] = (f16)(p2 * inv); pf[3] = (f16)(p3 * inv);
#pragma unroll
        for (int nt = 0; nt < 4; ++nt) {
            half4 vf = *(const half4*)(VT + win * 4096 + (size_t)(hq * 64 + nt * 16 + c) * 16 + g * 4);
            f32x4 o = MFMA16(vf, pf, z4);      // O^T[d][q]
            half4 oh;
#pragma unroll
            for (int r = 0; r < 4; ++r) oh[r] = (f16)o[r];
            of16[hq][nt] = oh;
        }
    }

    // ---- out-proj: OB^T[n][q] accumulated over 16 chunks of w_out rows ----
    f32x4 obacc[16];
#pragma unroll
    for (int i = 0; i < 16; ++i) obacc[i] = z4;
    __syncthreads();
#pragma unroll
    for (int ch = 0; ch < 8; ++ch) {
        if (ch < 7) stageW(wout, ch + 1, (ch + 1) & 1);
        else        stageW(wproj, 0, (ch + 1) & 1);
        int bsel = ch & 1;
#pragma unroll
        for (int ntl = 0; ntl < 2; ++ntl) {
            int nt2 = ch * 2 + ntl;
            int rowl = ntl * 16 + c;
            char* base = sm + bsel * 16384 + rowl * 512;
            int sw2 = (rowl & 15) << 3;
            f32x4 a = obacc[nt2];
#pragma unroll
            for (int hq = 0; hq < 4; ++hq)
#pragma unroll
                for (int dt = 0; dt < 4; ++dt) {
                    half4 wf = *(const half4*)(base + (((hq * 64 + dt * 16 + g * 4) * 2) ^ sw2));
                    a = MFMA16(wf, of16[hq][dt], a);
                }
            obacc[nt2] = a;
        }
        __syncthreads();
    }
    half4 obT[16];
#pragma unroll
    for (int nt = 0; nt < 16; ++nt) {
        f32x4 bv = *(const f32x4*)(outb + nt * 16 + g * 4);
        half4 h;
#pragma unroll
        for (int r = 0; r < 4; ++r) h[r] = (f16)(obacc[nt][r] + bv[r]);
        obT[nt] = h;
    }

    // ---- proj: Y^T[n_out][q] over 8 chunks of w_proj rows ----
    f32x4 yacc[16];
#pragma unroll
    for (int i = 0; i < 16; ++i) yacc[i] = z4;
#pragma unroll
    for (int pc = 0; pc < 8; ++pc) {
        if (pc < 7) stageW(wproj, pc + 1, (pc + 1) & 1);
        int bsel = pc & 1;
#pragma unroll
        for (int ntl = 0; ntl < 2; ++ntl) {
            int nt3 = pc * 2 + ntl;
            int rowl = ntl * 16 + c;
            char* base = sm + bsel * 16384 + rowl * 512;
            int sw2 = (rowl & 15) << 3;
            f32x4 a = yacc[nt3];
#pragma unroll
            for (int ntc = 0; ntc < 16; ++ntc) {
                half4 wf = *(const half4*)(base + (((ntc * 16 + g * 4) * 2) ^ sw2));
                a = MFMA16(wf, obT[ntc], a);
            }
            yacc[nt3] = a;
        }
        __syncthreads();
    }

    // ---- bias + exact GELU + store G ----
#pragma unroll
    for (int nt = 0; nt < 16; ++nt) {
        f32x4 bv = *(const f32x4*)(projb + nt * 16 + g * 4);
        half4 h;
#pragma unroll
        for (int r = 0; r < 4; ++r) {
            float x = yacc[nt][r] + bv[r];
            h[r] = (f16)(0.5f * x * (1.f + erff(x * 0.70710678118f)));
        }
        *(half4*)(G + (win * 16 + c) * 256 + nt * 16 + g * 4) = h;
    }
}

// ---------------- k4: residual + NCHW scatter, one block per full (bb,h) row ----------------
// Thread = (w, ch-quad-half). feat/out accesses are full-row 256B-coalesced along w with
// NO intra-row chunk boundaries (kills the R6 write amplification: 4 jh-chunks x misaligned
// 128B pieces -> 1.7x WRITE). G reads are 8B/lane scattered per instruction but L1-cached:
// each 64B G line serves 4 consecutive ci iterations; rolling window ~8KB/block << 32KB L1.
__global__ __launch_bounds__(256, 8)
void k4_out(const f16* __restrict__ G, const float* __restrict__ feat, float* __restrict__ outp) {
    const int tid = threadIdx.x;
    const int bid = blockIdx.x;            // bb*127 + h
    const int bb = bid / 127, h = bid % 127;
    const int w = tid & 127;               // 0..127 (w==127 masked: pad column)
    const int cq = tid >> 7;               // 0..1
    const bool wok = (w < 127);
    const size_t bbase = (size_t)bb * (256 * 127 * 127);
    // token index for (h, w): t = ((bb*32+wi)*4 + jh)*128 + wl4*16 + hh*4 + e
    const int wi = h >> 2, hh = h & 3;
    const int jh = w >> 5, wl4 = (w >> 2) & 7, e = w & 3;
    const size_t t = ((size_t)((bb * 32 + wi) * 4 + jh)) * 128 + wl4 * 16 + hh * 4 + e;
    const f16* gp = G + t * 256;
    const float* fp = feat + bbase + (size_t)h * 127 + w;
    float* op = outp + bbase + (size_t)h * 127 + w;
#pragma unroll 4
    for (int ci = 0; ci < 32; ++ci) {
        const int ch = ci * 8 + cq * 4;
        if (wok) {
            half4 g4 = *(const half4*)(gp + ch);
#pragma unroll
            for (int j = 0; j < 4; ++j) {
                size_t off = (size_t)(ch + j) * 16129;
                op[off] = fp[off] + (float)g4[j];
            }
        }
    }
}

extern "C" void kernel_launch(void* const* d_in, const int* in_sizes, int n_in,
                              void* d_out, int out_size, void* d_ws, size_t ws_size,
                              hipStream_t stream) {
    const float* feat   = (const float*)d_in[0];
    const float* ln_w   = (const float*)d_in[1];
    const float* ln_b   = (const float*)d_in[2];
    const float* in_w   = (const float*)d_in[3];
    const float* in_b   = (const float*)d_in[4];
    const float* out_w  = (const float*)d_in[5];
    const float* out_b  = (const float*)d_in[6];
    const float* proj_w = (const float*)d_in[7];
    const float* proj_b = (const float*)d_in[8];

    f16* W  = (f16*)d_ws;
    f16* Xb  = W + X0;
    f16* QKb = W + QK0;
    f16* VTb = W + VT0;
    f16* Gb  = Xb;   // reuse X region for G (X dead after k2)

    k0_cast<<<768, 256, 0, stream>>>(in_w, out_w, proj_w, W);
    k1_pack<<<1024, 256, 0, stream>>>(feat, ln_w, ln_b, Xb);
    k2_qkv<<<6144, 256, 0, stream>>>(Xb, W + W_IN0, in_b, QKb, VTb);
    k3_attn<<<2048, 256, 0, stream>>>(QKb, VTb, W + W_OUT0, W + W_PROJ0, out_b, proj_b, Gb);
    k4_out<<<1016, 256, 0, stream>>>(Gb, feat, (float*)d_out);
}

// Round 8
// 386.556 us; speedup vs baseline: 1.7700x; 1.1165x over previous
//
#include <hip/hip_runtime.h>

typedef _Float16 f16;
typedef __attribute__((ext_vector_type(4))) _Float16 half4;
typedef __attribute__((ext_vector_type(8))) _Float16 half8;
typedef __attribute__((ext_vector_type(4))) float f32x4;
typedef unsigned short u16;

#define MFMA32(a,b,c) __builtin_amdgcn_mfma_f32_16x16x32_f16(a,b,c,0,0,0)
#define MFMA16(a,b,c) __builtin_amdgcn_mfma_f32_16x16x16f16(a,b,c,0,0,0)

// ws layout (f16 element offsets)
#define W_IN0   0
#define W_OUT0  196608
#define W_PROJ0 262144
#define X0      327680
#define QK0     33882112ull
#define VT0     100990976ull

// ---------------- k0: cast weights to f16 ----------------
__global__ void k0_cast(const float* __restrict__ iw, const float* __restrict__ ow,
                        const float* __restrict__ pw, f16* __restrict__ W) {
    int i = blockIdx.x * 256 + threadIdx.x;
    if (i < 196608) W[W_IN0 + i] = (f16)iw[i];
    if (i < 65536) {
        W[W_OUT0 + i]  = (f16)ow[i];
        W[W_PROJ0 + i] = (f16)pw[i];
    }
}

// ---------------- k1: NCHW gather + LayerNorm -> X[t][256] f16 (no LDS, float4 loads) ----------------
// RULE #20 FIX (R7): arr[32] under "#pragma unroll 8" left a runtime base index ->
// whole array in scratch (VGPR_Count 36, WRITE 219MB vs 67 ideal). FULL unroll keeps
// every arr[] index compile-time -> lives in registers (~64 VGPR payload).
__global__ __launch_bounds__(256, 4)
void k1_pack(const float* __restrict__ feat, const float* __restrict__ lnw,
             const float* __restrict__ lnb, f16* __restrict__ X) {
    const int tid = threadIdx.x, lane = tid & 63, hh = tid >> 6;
    const int bid = blockIdx.x;
    const int jh = bid & 3, wi = (bid >> 2) & 31, bb = bid >> 7;
    const int h0 = wi * 4, w0 = jh * 32;
    const int wl4 = lane & 7, cg = lane >> 3;
    const int h = h0 + hh, wb = w0 + wl4 * 4;
    const bool hok = (h < 127);
    const bool edge = (wb + 3) >= 127;      // only jh==3 && wl4==7 (w=127 is pad)
    const size_t bbase = (size_t)bb * (256 * 127 * 127);
    const int c0 = cg * 32;
    const float* p0 = feat + bbase + (size_t)c0 * 16129 + (size_t)h * 127 + wb;

    half4 arr[32];                           // [ch within group][token e], f16 pre-LN
    float ss[4] = {0.f, 0.f, 0.f, 0.f}, qq[4] = {0.f, 0.f, 0.f, 0.f};
    if (hok && !edge) {
#pragma unroll
        for (int i = 0; i < 32; ++i) {
            f32x4 v = *(const f32x4*)(p0 + (size_t)i * 16129);
            half4 hv;
#pragma unroll
            for (int e = 0; e < 4; ++e) { ss[e] += v[e]; qq[e] += v[e] * v[e]; hv[e] = (f16)v[e]; }
            arr[i] = hv;
        }
    } else if (hok) {
#pragma unroll
        for (int i = 0; i < 32; ++i) {
            const float* pi = p0 + (size_t)i * 16129;
            half4 hv;
#pragma unroll
            for (int e = 0; e < 3; ++e) { float v = pi[e]; ss[e] += v; qq[e] += v * v; hv[e] = (f16)v; }
            hv[3] = (f16)0.f;
            arr[i] = hv;
        }
    } else {
#pragma unroll
        for (int i = 0; i < 32; ++i) {
            half4 hv; hv[0] = hv[1] = hv[2] = hv[3] = (f16)0.f; arr[i] = hv;
        }
    }
#pragma unroll
    for (int e = 0; e < 4; ++e) {
        ss[e] += __shfl_xor(ss[e], 8);  qq[e] += __shfl_xor(qq[e], 8);
        ss[e] += __shfl_xor(ss[e], 16); qq[e] += __shfl_xor(qq[e], 16);
        ss[e] += __shfl_xor(ss[e], 32); qq[e] += __shfl_xor(qq[e], 32);
    }
    float mu[4], rs[4];
#pragma unroll
    for (int e = 0; e < 4; ++e) {
        mu[e] = ss[e] * (1.f / 256.f);
        rs[e] = rsqrtf(qq[e] * (1.f / 256.f) - mu[e] * mu[e] + 1e-5f);
    }
#pragma unroll
    for (int q = 0; q < 4; ++q) {
        f32x4 lw0 = *(const f32x4*)(lnw + c0 + q * 8);
        f32x4 lw1 = *(const f32x4*)(lnw + c0 + q * 8 + 4);
        f32x4 lb0 = *(const f32x4*)(lnb + c0 + q * 8);
        f32x4 lb1 = *(const f32x4*)(lnb + c0 + q * 8 + 4);
#pragma unroll
        for (int e = 0; e < 4; ++e) {
            const int m = wl4 * 16 + hh * 4 + e;
            f16* xrow = X + ((size_t)bid * 128 + m) * 256 + c0;
            half8 o;
#pragma unroll
            for (int j = 0; j < 4; ++j) {
                o[j]     = (f16)(((float)arr[q * 8 + j][e]     - mu[e]) * rs[e] * lw0[j] + lb0[j]);
                o[j + 4] = (f16)(((float)arr[q * 8 + j + 4][e] - mu[e]) * rs[e] * lw1[j] + lb1[j]);
            }
            *(half8*)(xrow + q * 8) = o;
        }
    }
}

// ---------------- k2: QKV GEMM  X[131072x256] @ in_w^T -> QK / VT ----------------
__global__ __launch_bounds__(256, 2)
void k2_qkv(const f16* __restrict__ X, const f16* __restrict__ win,
            const float* __restrict__ inb, f16* __restrict__ QK, f16* __restrict__ VT) {
    __shared__ __align__(16) char sm[65536];   // 2 bufs x (A 16K | B 16K)
    const int tid = threadIdx.x, lane = tid & 63, wv = tid >> 6;
    // XCD-aware swizzle (T1): consecutive logical bids (same A-tile) land on one XCD.
    const int nwg = gridDim.x;                 // 6144, divisible by 8
    const int bid = (blockIdx.x & 7) * (nwg >> 3) + (blockIdx.x >> 3);
    const int mt = bid / 6, nb = bid % 6;
    const size_t Mbase = (size_t)mt * 128;
    const int n0 = nb * 128;
    const int wm = wv >> 1, wn = wv & 1;
    const int c = lane & 15, g = lane >> 4;
    const int r8 = lane >> 3, chv = lane & 7;

    f32x4 acc[4][4];
#pragma unroll
    for (int a = 0; a < 4; ++a)
#pragma unroll
        for (int b = 0; b < 4; ++b) acc[a][b] = f32x4{0.f, 0.f, 0.f, 0.f};

    auto stage = [&](int step, int bsel) {
        const f16* As = X + Mbase * 256 + step * 64;
        const f16* Bs = win + (size_t)n0 * 256 + step * 64;
#pragma unroll
        for (int q = 0; q < 4; ++q) {
            int ia = wv * 4 + q;
            int row = ia * 8 + r8;
            int chs = chv ^ (row & 7);
            __builtin_amdgcn_global_load_lds(
                (const __attribute__((address_space(1))) unsigned int*)(As + (size_t)row * 256 + chs * 8),
                (__attribute__((address_space(3))) unsigned int*)(sm + bsel * 32768 + ia * 1024),
                16, 0, 0);
            __builtin_amdgcn_global_load_lds(
                (const __attribute__((address_space(1))) unsigned int*)(Bs + (size_t)row * 256 + chs * 8),
                (__attribute__((address_space(3))) unsigned int*)(sm + bsel * 32768 + 16384 + ia * 1024),
                16, 0, 0);
        }
    };
    stage(0, 0);
    __syncthreads();
    for (int s = 0; s < 4; ++s) {
        int bsel = s & 1;
        if (s < 3) stage(s + 1, bsel ^ 1);
#pragma unroll
        for (int kk2 = 0; kk2 < 2; ++kk2) {
            half8 a[4], b[4];
#pragma unroll
            for (int mi = 0; mi < 4; ++mi) {
                int row = wm * 64 + mi * 16 + c;
                a[mi] = *(half8*)(sm + bsel * 32768 + row * 128 + ((kk2 * 64 + g * 16) ^ ((row & 7) << 4)));
            }
#pragma unroll
            for (int nt = 0; nt < 4; ++nt) {
                int row = wn * 64 + nt * 16 + c;
                b[nt] = *(half8*)(sm + bsel * 32768 + 16384 + row * 128 + ((kk2 * 64 + g * 16) ^ ((row & 7) << 4)));
            }
#pragma unroll
            for (int mi = 0; mi < 4; ++mi)
#pragma unroll
                for (int nt = 0; nt < 4; ++nt)
                    acc[mi][nt] = MFMA32(a[mi], b[nt], acc[mi][nt]);
        }
        __syncthreads();
    }

    const f32x4 z4 = {0.f, 0.f, 0.f, 0.f};
    half4 idf;
#pragma unroll
    for (int j = 0; j < 4; ++j) idf[j] = (f16)((g * 4 + j == c) ? 1.f : 0.f);

    if (n0 < 512) {
        // Q,K: transpose via identity mfma, store row-major QK[t][512]
#pragma unroll
        for (int mi = 0; mi < 4; ++mi)
#pragma unroll
            for (int nt = 0; nt < 4; ++nt) {
                int n = n0 + wn * 64 + nt * 16 + c;
                float bias = inb[n];
                half4 h;
#pragma unroll
                for (int r = 0; r < 4; ++r) h[r] = (f16)(acc[mi][nt][r] + bias);
                f32x4 t = MFMA16(h, idf, z4);      // C/D-as-A (=T^T) times I -> transposed tile
                half4 o;
#pragma unroll
                for (int r = 0; r < 4; ++r) o[r] = (f16)t[r];
                size_t tok = Mbase + wm * 64 + mi * 16 + c;       // col of transposed tile = m
                *(half4*)(QK + tok * 512 + (n0 + wn * 64 + nt * 16 + g * 4)) = o;
            }
    } else {
        // V: store [win][d][t] directly from C/D (rows = 4 contiguous tokens)
#pragma unroll
        for (int mi = 0; mi < 4; ++mi)
#pragma unroll
            for (int nt = 0; nt < 4; ++nt) {
                int n = n0 + wn * 64 + nt * 16 + c;
                float bias = inb[n];
                half4 h;
#pragma unroll
                for (int r = 0; r < 4; ++r) h[r] = (f16)(acc[mi][nt][r] + bias);
                int d = n - 512;
                size_t tokb = Mbase + wm * 64 + mi * 16;          // window-aligned
                size_t winI = tokb >> 4;
                *(half4*)(VT + winI * 4096 + (size_t)d * 16 + g * 4) = h;
            }
    }
}

// ---------------- k3: attention + out-proj + proj + GELU -> G[t][256] f16 ----------------
// launch_bounds(256,3): budget 170 regs/wave; gfx950 splits unified file ~half arch / half
// accum for MFMA kernels -> arch ~84 = natural usage, NO spill. (256,4) gave arch 64 ->
// spill (R5: WRITE 386MB); (256,5) gave 48 -> heavy spill (R4). Do not lower the budget.
__global__ __launch_bounds__(256, 3)
void k3_attn(const f16* __restrict__ QK, const f16* __restrict__ VT,
             const f16* __restrict__ wout, const f16* __restrict__ wproj,
             const float* __restrict__ outb, const float* __restrict__ projb,
             f16* __restrict__ G) {
    __shared__ __align__(16) char sm[32768];   // 2 x 16KB weight chunks [32 n][256 d], 4-bit XOR swizzle
    const int tid = threadIdx.x, lane = tid & 63, wv = tid >> 6;
    const int c = lane & 15, g = lane >> 4;
    const size_t win = (size_t)blockIdx.x * 4 + wv;
    const f16* qrow = QK + (win * 16 + c) * 512;
    const f32x4 z4 = {0.f, 0.f, 0.f, 0.f};

    const int nl = tid >> 3, seg = tid & 7;
    const int swz = (nl & 15) << 3;            // bits 3-6: spreads 16 rows over 16 8B-slots
    auto stageW = [&](const f16* mat, int rc, int bsel) {
        const f16* src = mat + ((size_t)(rc * 32 + nl)) * 256 + seg * 32;
        char* dst = sm + bsel * 16384 + nl * 512;
#pragma unroll
        for (int i = 0; i < 4; ++i) {
            uint4 u = *(const uint4*)(src + i * 8);
            int b0 = (seg * 64 + i * 16) ^ swz;
            int b1 = (seg * 64 + i * 16 + 8) ^ swz;
            *(uint2*)(dst + b0) = make_uint2(u.x, u.y);
            *(uint2*)(dst + b1) = make_uint2(u.z, u.w);
        }
    };

    stageW(wout, 0, 0);   // chunk 0 in flight under attention

    // ---- attention, all in registers ----
    half4 of16[4][4];
#pragma unroll
    for (int hq = 0; hq < 4; ++hq) {
        half8 af0 = *(const half8*)(qrow + 256 + hq * 64 + g * 8);
        half8 af1 = *(const half8*)(qrow + 256 + hq * 64 + 32 + g * 8);
        half8 bq0 = *(const half8*)(qrow + hq * 64 + g * 8);
        half8 bq1 = *(const half8*)(qrow + hq * 64 + 32 + g * 8);
        f32x4 sacc = MFMA32(af0, bq0, z4);     // S^T[k_tok][q]
        sacc = MFMA32(af1, bq1, sacc);
        float s0 = sacc[0] * 0.125f, s1 = sacc[1] * 0.125f;
        float s2 = sacc[2] * 0.125f, s3 = sacc[3] * 0.125f;
        float mx = fmaxf(fmaxf(s0, s1), fmaxf(s2, s3));
        mx = fmaxf(mx, __shfl_xor(mx, 16));
        mx = fmaxf(mx, __shfl_xor(mx, 32));
        float p0 = __expf(s0 - mx), p1 = __expf(s1 - mx);
        float p2 = __expf(s2 - mx), p3 = __expf(s3 - mx);
        float sum = p0 + p1 + p2 + p3;
        sum += __shfl_xor(sum, 16);
        sum += __shfl_xor(sum, 32);
        float inv = 1.f / sum;
        half4 pf;
        pf[0] = (f16)(p0 * inv); pf[1] = (f16)(p1 * inv);
        pf[2] = (f16)(p2 * inv); pf[3] = (f16)(p3 * inv);
#pragma unroll
        for (int nt = 0; nt < 4; ++nt) {
            half4 vf = *(const half4*)(VT + win * 4096 + (size_t)(hq * 64 + nt * 16 + c) * 16 + g * 4);
            f32x4 o = MFMA16(vf, pf, z4);      // O^T[d][q]
            half4 oh;
#pragma unroll
            for (int r = 0; r < 4; ++r) oh[r] = (f16)o[r];
            of16[hq][nt] = oh;
        }
    }

    // ---- out-proj: OB^T[n][q] accumulated over 16 chunks of w_out rows ----
    f32x4 obacc[16];
#pragma unroll
    for (int i = 0; i < 16; ++i) obacc[i] = z4;
    __syncthreads();
#pragma unroll
    for (int ch = 0; ch < 8; ++ch) {
        if (ch < 7) stageW(wout, ch + 1, (ch + 1) & 1);
        else        stageW(wproj, 0, (ch + 1) & 1);
        int bsel = ch & 1;
#pragma unroll
        for (int ntl = 0; ntl < 2; ++ntl) {
            int nt2 = ch * 2 + ntl;
            int rowl = ntl * 16 + c;
            char* base = sm + bsel * 16384 + rowl * 512;
            int sw2 = (rowl & 15) << 3;
            f32x4 a = obacc[nt2];
#pragma unroll
            for (int hq = 0; hq < 4; ++hq)
#pragma unroll
                for (int dt = 0; dt < 4; ++dt) {
                    half4 wf = *(const half4*)(base + (((hq * 64 + dt * 16 + g * 4) * 2) ^ sw2));
                    a = MFMA16(wf, of16[hq][dt], a);
                }
            obacc[nt2] = a;
        }
        __syncthreads();
    }
    half4 obT[16];
#pragma unroll
    for (int nt = 0; nt < 16; ++nt) {
        f32x4 bv = *(const f32x4*)(outb + nt * 16 + g * 4);
        half4 h;
#pragma unroll
        for (int r = 0; r < 4; ++r) h[r] = (f16)(obacc[nt][r] + bv[r]);
        obT[nt] = h;
    }

    // ---- proj: Y^T[n_out][q] over 8 chunks of w_proj rows ----
    f32x4 yacc[16];
#pragma unroll
    for (int i = 0; i < 16; ++i) yacc[i] = z4;
#pragma unroll
    for (int pc = 0; pc < 8; ++pc) {
        if (pc < 7) stageW(wproj, pc + 1, (pc + 1) & 1);
        int bsel = pc & 1;
#pragma unroll
        for (int ntl = 0; ntl < 2; ++ntl) {
            int nt3 = pc * 2 + ntl;
            int rowl = ntl * 16 + c;
            char* base = sm + bsel * 16384 + rowl * 512;
            int sw2 = (rowl & 15) << 3;
            f32x4 a = yacc[nt3];
#pragma unroll
            for (int ntc = 0; ntc < 16; ++ntc) {
                half4 wf = *(const half4*)(base + (((ntc * 16 + g * 4) * 2) ^ sw2));
                a = MFMA16(wf, obT[ntc], a);
            }
            yacc[nt3] = a;
        }
        __syncthreads();
    }

    // ---- bias + exact GELU + store G ----
#pragma unroll
    for (int nt = 0; nt < 16; ++nt) {
        f32x4 bv = *(const f32x4*)(projb + nt * 16 + g * 4);
        half4 h;
#pragma unroll
        for (int r = 0; r < 4; ++r) {
            float x = yacc[nt][r] + bv[r];
            h[r] = (f16)(0.5f * x * (1.f + erff(x * 0.70710678118f)));
        }
        *(half4*)(G + (win * 16 + c) * 256 + nt * 16 + g * 4) = h;
    }
}

// ---------------- k4: residual + NCHW scatter, one block per full (bb,h) row ----------------
__global__ __launch_bounds__(256, 8)
void k4_out(const f16* __restrict__ G, const float* __restrict__ feat, float* __restrict__ outp) {
    const int tid = threadIdx.x;
    const int bid = blockIdx.x;            // bb*127 + h
    const int bb = bid / 127, h = bid % 127;
    const int w = tid & 127;               // 0..127 (w==127 masked: pad column)
    const int cq = tid >> 7;               // 0..1
    const bool wok = (w < 127);
    const size_t bbase = (size_t)bb * (256 * 127 * 127);
    // token index for (h, w): t = ((bb*32+wi)*4 + jh)*128 + wl4*16 + hh*4 + e
    const int wi = h >> 2, hh = h & 3;
    const int jh = w >> 5, wl4 = (w >> 2) & 7, e = w & 3;
    const size_t t = ((size_t)((bb * 32 + wi) * 4 + jh)) * 128 + wl4 * 16 + hh * 4 + e;
    const f16* gp = G + t * 256;
    const float* fp = feat + bbase + (size_t)h * 127 + w;
    float* op = outp + bbase + (size_t)h * 127 + w;
#pragma unroll 4
    for (int ci = 0; ci < 32; ++ci) {
        const int ch = ci * 8 + cq * 4;
        if (wok) {
            half4 g4 = *(const half4*)(gp + ch);
#pragma unroll
            for (int j = 0; j < 4; ++j) {
                size_t off = (size_t)(ch + j) * 16129;
                op[off] = fp[off] + (float)g4[j];
            }
        }
    }
}

extern "C" void kernel_launch(void* const* d_in, const int* in_sizes, int n_in,
                              void* d_out, int out_size, void* d_ws, size_t ws_size,
                              hipStream_t stream) {
    const float* feat   = (const float*)d_in[0];
    const float* ln_w   = (const float*)d_in[1];
    const float* ln_b   = (const float*)d_in[2];
    const float* in_w   = (const float*)d_in[3];
    const float* in_b   = (const float*)d_in[4];
    const float* out_w  = (const float*)d_in[5];
    const float* out_b  = (const float*)d_in[6];
    const float* proj_w = (const float*)d_in[7];
    const float* proj_b = (const float*)d_in[8];

    f16* W  = (f16*)d_ws;
    f16* Xb  = W + X0;
    f16* QKb = W + QK0;
    f16* VTb = W + VT0;
    f16* Gb  = Xb;   // reuse X region for G (X dead after k2)

    k0_cast<<<768, 256, 0, stream>>>(in_w, out_w, proj_w, W);
    k1_pack<<<1024, 256, 0, stream>>>(feat, ln_w, ln_b, Xb);
    k2_qkv<<<6144, 256, 0, stream>>>(Xb, W + W_IN0, in_b, QKb, VTb);
    k3_attn<<<2048, 256, 0, stream>>>(QKb, VTb, W + W_OUT0, W + W_PROJ0, out_b, proj_b, Gb);
    k4_out<<<1016, 256, 0, stream>>>(Gb, feat, (float*)d_out);
}

// Round 9
// 367.032 us; speedup vs baseline: 1.8641x; 1.0532x over previous
//
#include <hip/hip_runtime.h>

typedef _Float16 f16;
typedef __attribute__((ext_vector_type(4))) _Float16 half4;
typedef __attribute__((ext_vector_type(8))) _Float16 half8;
typedef __attribute__((ext_vector_type(4))) float f32x4;
typedef unsigned short u16;

#define MFMA32(a,b,c) __builtin_amdgcn_mfma_f32_16x16x32_f16(a,b,c,0,0,0)
#define MFMA16(a,b,c) __builtin_amdgcn_mfma_f32_16x16x16f16(a,b,c,0,0,0)

// ws layout (f16 element offsets)
#define W_IN0   0
#define W_OUT0  196608
#define W_PROJ0 262144
#define X0      327680
#define QK0     33882112ull
#define VT0     100990976ull

// ---------------- k0: cast weights to f16; build permuted+swizzled images for w_out/w_proj ----
// Image layout (per matrix, 8 chunks x 32 rows x 256 f16): chunk rc at rc*8192, row nl at
// nl*256, 16B slot sp at sp*8. Slot sp = (kc*4+g)^(nl&7) holds [W[r][kc*32+g*4+0..3],
// W[r][kc*32+16+g*4+0..3]] -- i.e. the MFMA32 A-fragment bytes, pre-XOR-swizzled so k3 can
// stage with LINEAR global_load_lds (rule #21) and read conflict-balanced ds_read_b128.
__global__ void k0_cast(const float* __restrict__ iw, const float* __restrict__ ow,
                        const float* __restrict__ pw, f16* __restrict__ W) {
    int i = blockIdx.x * 256 + threadIdx.x;
    if (i < 196608) W[W_IN0 + i] = (f16)iw[i];
    if (i < 16384) {
        const int s = i & 8191;
        const float* src = (i < 8192) ? ow : pw;
        f16* dst = W + ((i < 8192) ? W_OUT0 : W_PROJ0);
        const int r = s >> 5, sp = s & 31;
        const int u = sp ^ (r & 7);
        const int kc = u >> 2, gg = u & 3;
        const int c0 = kc * 32 + gg * 4;
        f32x4 v0 = *(const f32x4*)(src + r * 256 + c0);
        f32x4 v1 = *(const f32x4*)(src + r * 256 + c0 + 16);
        half8 o;
#pragma unroll
        for (int j = 0; j < 4; ++j) { o[j] = (f16)v0[j]; o[j + 4] = (f16)v1[j]; }
        *(half8*)(dst + (r >> 5) * 8192 + (r & 31) * 256 + sp * 8) = o;
    }
}

// ---------------- k1: NCHW gather + LayerNorm -> X[t][256] f16 (no LDS, float4 loads) ----------------
__global__ __launch_bounds__(256, 4)
void k1_pack(const float* __restrict__ feat, const float* __restrict__ lnw,
             const float* __restrict__ lnb, f16* __restrict__ X) {
    const int tid = threadIdx.x, lane = tid & 63, hh = tid >> 6;
    const int bid = blockIdx.x;
    const int jh = bid & 3, wi = (bid >> 2) & 31, bb = bid >> 7;
    const int h0 = wi * 4, w0 = jh * 32;
    const int wl4 = lane & 7, cg = lane >> 3;
    const int h = h0 + hh, wb = w0 + wl4 * 4;
    const bool hok = (h < 127);
    const bool edge = (wb + 3) >= 127;      // only jh==3 && wl4==7 (w=127 is pad)
    const size_t bbase = (size_t)bb * (256 * 127 * 127);
    const int c0 = cg * 32;
    const float* p0 = feat + bbase + (size_t)c0 * 16129 + (size_t)h * 127 + wb;

    half4 arr[32];                           // [ch within group][token e], f16 pre-LN
    float ss[4] = {0.f, 0.f, 0.f, 0.f}, qq[4] = {0.f, 0.f, 0.f, 0.f};
    if (hok && !edge) {
#pragma unroll
        for (int i = 0; i < 32; ++i) {
            f32x4 v = *(const f32x4*)(p0 + (size_t)i * 16129);
            half4 hv;
#pragma unroll
            for (int e = 0; e < 4; ++e) { ss[e] += v[e]; qq[e] += v[e] * v[e]; hv[e] = (f16)v[e]; }
            arr[i] = hv;
        }
    } else if (hok) {
#pragma unroll
        for (int i = 0; i < 32; ++i) {
            const float* pi = p0 + (size_t)i * 16129;
            half4 hv;
#pragma unroll
            for (int e = 0; e < 3; ++e) { float v = pi[e]; ss[e] += v; qq[e] += v * v; hv[e] = (f16)v; }
            hv[3] = (f16)0.f;
            arr[i] = hv;
        }
    } else {
#pragma unroll
        for (int i = 0; i < 32; ++i) {
            half4 hv; hv[0] = hv[1] = hv[2] = hv[3] = (f16)0.f; arr[i] = hv;
        }
    }
#pragma unroll
    for (int e = 0; e < 4; ++e) {
        ss[e] += __shfl_xor(ss[e], 8);  qq[e] += __shfl_xor(qq[e], 8);
        ss[e] += __shfl_xor(ss[e], 16); qq[e] += __shfl_xor(qq[e], 16);
        ss[e] += __shfl_xor(ss[e], 32); qq[e] += __shfl_xor(qq[e], 32);
    }
    float mu[4], rs[4];
#pragma unroll
    for (int e = 0; e < 4; ++e) {
        mu[e] = ss[e] * (1.f / 256.f);
        rs[e] = rsqrtf(qq[e] * (1.f / 256.f) - mu[e] * mu[e] + 1e-5f);
    }
#pragma unroll
    for (int q = 0; q < 4; ++q) {
        f32x4 lw0 = *(const f32x4*)(lnw + c0 + q * 8);
        f32x4 lw1 = *(const f32x4*)(lnw + c0 + q * 8 + 4);
        f32x4 lb0 = *(const f32x4*)(lnb + c0 + q * 8);
        f32x4 lb1 = *(const f32x4*)(lnb + c0 + q * 8 + 4);
#pragma unroll
        for (int e = 0; e < 4; ++e) {
            const int m = wl4 * 16 + hh * 4 + e;
            f16* xrow = X + ((size_t)bid * 128 + m) * 256 + c0;
            half8 o;
#pragma unroll
            for (int j = 0; j < 4; ++j) {
                o[j]     = (f16)(((float)arr[q * 8 + j][e]     - mu[e]) * rs[e] * lw0[j] + lb0[j]);
                o[j + 4] = (f16)(((float)arr[q * 8 + j + 4][e] - mu[e]) * rs[e] * lw1[j] + lb1[j]);
            }
            *(half8*)(xrow + q * 8) = o;
        }
    }
}

// ---------------- k2: QKV GEMM  X[131072x256] @ in_w^T -> QK / VT ----------------
__global__ __launch_bounds__(256, 2)
void k2_qkv(const f16* __restrict__ X, const f16* __restrict__ win,
            const float* __restrict__ inb, f16* __restrict__ QK, f16* __restrict__ VT) {
    __shared__ __align__(16) char sm[65536];   // 2 bufs x (A 16K | B 16K)
    const int tid = threadIdx.x, lane = tid & 63, wv = tid >> 6;
    // XCD-aware swizzle (T1): consecutive logical bids (same A-tile) land on one XCD.
    const int nwg = gridDim.x;                 // 6144, divisible by 8
    const int bid = (blockIdx.x & 7) * (nwg >> 3) + (blockIdx.x >> 3);
    const int mt = bid / 6, nb = bid % 6;
    const size_t Mbase = (size_t)mt * 128;
    const int n0 = nb * 128;
    const int wm = wv >> 1, wn = wv & 1;
    const int c = lane & 15, g = lane >> 4;
    const int r8 = lane >> 3, chv = lane & 7;

    f32x4 acc[4][4];
#pragma unroll
    for (int a = 0; a < 4; ++a)
#pragma unroll
        for (int b = 0; b < 4; ++b) acc[a][b] = f32x4{0.f, 0.f, 0.f, 0.f};

    auto stage = [&](int step, int bsel) {
        const f16* As = X + Mbase * 256 + step * 64;
        const f16* Bs = win + (size_t)n0 * 256 + step * 64;
#pragma unroll
        for (int q = 0; q < 4; ++q) {
            int ia = wv * 4 + q;
            int row = ia * 8 + r8;
            int chs = chv ^ (row & 7);
            __builtin_amdgcn_global_load_lds(
                (const __attribute__((address_space(1))) unsigned int*)(As + (size_t)row * 256 + chs * 8),
                (__attribute__((address_space(3))) unsigned int*)(sm + bsel * 32768 + ia * 1024),
                16, 0, 0);
            __builtin_amdgcn_global_load_lds(
                (const __attribute__((address_space(1))) unsigned int*)(Bs + (size_t)row * 256 + chs * 8),
                (__attribute__((address_space(3))) unsigned int*)(sm + bsel * 32768 + 16384 + ia * 1024),
                16, 0, 0);
        }
    };
    stage(0, 0);
    __syncthreads();
    for (int s = 0; s < 4; ++s) {
        int bsel = s & 1;
        if (s < 3) stage(s + 1, bsel ^ 1);
#pragma unroll
        for (int kk2 = 0; kk2 < 2; ++kk2) {
            half8 a[4], b[4];
#pragma unroll
            for (int mi = 0; mi < 4; ++mi) {
                int row = wm * 64 + mi * 16 + c;
                a[mi] = *(half8*)(sm + bsel * 32768 + row * 128 + ((kk2 * 64 + g * 16) ^ ((row & 7) << 4)));
            }
#pragma unroll
            for (int nt = 0; nt < 4; ++nt) {
                int row = wn * 64 + nt * 16 + c;
                b[nt] = *(half8*)(sm + bsel * 32768 + 16384 + row * 128 + ((kk2 * 64 + g * 16) ^ ((row & 7) << 4)));
            }
#pragma unroll
            for (int mi = 0; mi < 4; ++mi)
#pragma unroll
                for (int nt = 0; nt < 4; ++nt)
                    acc[mi][nt] = MFMA32(a[mi], b[nt], acc[mi][nt]);
        }
        __syncthreads();
    }

    const f32x4 z4 = {0.f, 0.f, 0.f, 0.f};
    half4 idf;
#pragma unroll
    for (int j = 0; j < 4; ++j) idf[j] = (f16)((g * 4 + j == c) ? 1.f : 0.f);

    if (n0 < 512) {
        // Q,K: transpose via identity mfma, store row-major QK[t][512]
#pragma unroll
        for (int mi = 0; mi < 4; ++mi)
#pragma unroll
            for (int nt = 0; nt < 4; ++nt) {
                int n = n0 + wn * 64 + nt * 16 + c;
                float bias = inb[n];
                half4 h;
#pragma unroll
                for (int r = 0; r < 4; ++r) h[r] = (f16)(acc[mi][nt][r] + bias);
                f32x4 t = MFMA16(h, idf, z4);      // C/D-as-A (=T^T) times I -> transposed tile
                half4 o;
#pragma unroll
                for (int r = 0; r < 4; ++r) o[r] = (f16)t[r];
                size_t tok = Mbase + wm * 64 + mi * 16 + c;       // col of transposed tile = m
                *(half4*)(QK + tok * 512 + (n0 + wn * 64 + nt * 16 + g * 4)) = o;
            }
    } else {
        // V: store [win][d][t] directly from C/D (rows = 4 contiguous tokens)
#pragma unroll
        for (int mi = 0; mi < 4; ++mi)
#pragma unroll
            for (int nt = 0; nt < 4; ++nt) {
                int n = n0 + wn * 64 + nt * 16 + c;
                float bias = inb[n];
                half4 h;
#pragma unroll
                for (int r = 0; r < 4; ++r) h[r] = (f16)(acc[mi][nt][r] + bias);
                int d = n - 512;
                size_t tokb = Mbase + wm * 64 + mi * 16;          // window-aligned
                size_t winI = tokb >> 4;
                *(half4*)(VT + winI * 4096 + (size_t)d * 16 + g * 4) = h;
            }
    }
}

// ---------------- k3: attention + out-proj + proj + GELU -> G[t][256] f16 ----------------
// MFMA32 everywhere in the GEMMs: weights pre-permuted (k0) so the packed lane-local
// activation fragments [frag_2t | frag_2t+1] are valid 16x16x32 B-operands; weight image
// pre-swizzled so staging is linear global_load_lds and ds_read_b128 is conflict-balanced
// (8 lanes/bank-group, distinct rows). Accumulators converted per-chunk (8 live VGPR).
// launch_bounds(256,3): do NOT lower (R4/R5 spill lesson).
__global__ __launch_bounds__(256, 3)
void k3_attn(const f16* __restrict__ QK, const f16* __restrict__ VT,
             const f16* __restrict__ wout, const f16* __restrict__ wproj,
             const float* __restrict__ outb, const float* __restrict__ projb,
             f16* __restrict__ G) {
    __shared__ __align__(16) char sm[32768];   // 2 x 16KB weight chunks (pre-swizzled image)
    const int tid = threadIdx.x, lane = tid & 63, wv = tid >> 6;
    const int c = lane & 15, g = lane >> 4;
    const size_t win = (size_t)blockIdx.x * 4 + wv;
    const f16* qrow = QK + (win * 16 + c) * 512;
    const f32x4 z4 = {0.f, 0.f, 0.f, 0.f};

    auto stageW = [&](const f16* img, int rc, int bsel) {
#pragma unroll
        for (int q2 = 0; q2 < 4; ++q2) {
            int ia = wv * 4 + q2;
            __builtin_amdgcn_global_load_lds(
                (const __attribute__((address_space(1))) unsigned int*)(img + rc * 8192 + ia * 512 + lane * 8),
                (__attribute__((address_space(3))) unsigned int*)(sm + bsel * 16384 + ia * 1024),
                16, 0, 0);
        }
    };

    stageW(wout, 0, 0);   // chunk 0 in flight under attention

    // ---- attention, all in registers; pack PV outputs as MFMA32 B-frags ofp[hq][t] ----
    half8 ofp[4][2];
#pragma unroll
    for (int hq = 0; hq < 4; ++hq) {
        half8 af0 = *(const half8*)(qrow + 256 + hq * 64 + g * 8);
        half8 af1 = *(const half8*)(qrow + 256 + hq * 64 + 32 + g * 8);
        half8 bq0 = *(const half8*)(qrow + hq * 64 + g * 8);
        half8 bq1 = *(const half8*)(qrow + hq * 64 + 32 + g * 8);
        f32x4 sacc = MFMA32(af0, bq0, z4);     // S^T[k_tok][q]
        sacc = MFMA32(af1, bq1, sacc);
        float s0 = sacc[0] * 0.125f, s1 = sacc[1] * 0.125f;
        float s2 = sacc[2] * 0.125f, s3 = sacc[3] * 0.125f;
        float mx = fmaxf(fmaxf(s0, s1), fmaxf(s2, s3));
        mx = fmaxf(mx, __shfl_xor(mx, 16));
        mx = fmaxf(mx, __shfl_xor(mx, 32));
        float p0 = __expf(s0 - mx), p1 = __expf(s1 - mx);
        float p2 = __expf(s2 - mx), p3 = __expf(s3 - mx);
        float sum = p0 + p1 + p2 + p3;
        sum += __shfl_xor(sum, 16);
        sum += __shfl_xor(sum, 32);
        float inv = 1.f / sum;
        half4 pf;
        pf[0] = (f16)(p0 * inv); pf[1] = (f16)(p1 * inv);
        pf[2] = (f16)(p2 * inv); pf[3] = (f16)(p3 * inv);
#pragma unroll
        for (int nt = 0; nt < 4; ++nt) {
            half4 vf = *(const half4*)(VT + win * 4096 + (size_t)(hq * 64 + nt * 16 + c) * 16 + g * 4);
            f32x4 o = MFMA16(vf, pf, z4);      // O^T[d][q]
#pragma unroll
            for (int r = 0; r < 4; ++r) ofp[hq][nt >> 1][(nt & 1) * 4 + r] = (f16)o[r];
        }
    }

    const int r0 = c, r1 = 16 + c;
    const int sw0 = (r0 & 7) << 4, sw1 = (r1 & 7) << 4;
    half8 obp[8];
    __syncthreads();

    // ---- out-proj: per 32-row weight chunk, 8 k-chunks of 32 via MFMA32 ----
#pragma unroll
    for (int ch = 0; ch < 8; ++ch) {
        if (ch < 7) stageW(wout, ch + 1, (ch + 1) & 1);
        else        stageW(wproj, 0, (ch + 1) & 1);
        char* base = sm + (ch & 1) * 16384;
        f32x4 a0 = z4, a1 = z4;
#pragma unroll
        for (int kc = 0; kc < 8; ++kc) {
            half8 w0 = *(half8*)(base + r0 * 512 + ((kc * 64 + g * 16) ^ sw0));
            a0 = MFMA32(w0, ofp[kc >> 1][kc & 1], a0);
            half8 w1 = *(half8*)(base + r1 * 512 + ((kc * 64 + g * 16) ^ sw1));
            a1 = MFMA32(w1, ofp[kc >> 1][kc & 1], a1);
        }
        f32x4 b0 = *(const f32x4*)(outb + ch * 32 + g * 4);
        f32x4 b1 = *(const f32x4*)(outb + ch * 32 + 16 + g * 4);
#pragma unroll
        for (int r = 0; r < 4; ++r) {
            obp[ch][r]     = (f16)(a0[r] + b0[r]);
            obp[ch][4 + r] = (f16)(a1[r] + b1[r]);
        }
        __syncthreads();
    }

    // ---- proj + bias + exact GELU + store G ----
#pragma unroll
    for (int pc = 0; pc < 8; ++pc) {
        if (pc < 7) stageW(wproj, pc + 1, (pc + 1) & 1);
        char* base = sm + (pc & 1) * 16384;
        f32x4 a0 = z4, a1 = z4;
#pragma unroll
        for (int kc = 0; kc < 8; ++kc) {
            half8 w0 = *(half8*)(base + r0 * 512 + ((kc * 64 + g * 16) ^ sw0));
            a0 = MFMA32(w0, obp[kc], a0);
            half8 w1 = *(half8*)(base + r1 * 512 + ((kc * 64 + g * 16) ^ sw1));
            a1 = MFMA32(w1, obp[kc], a1);
        }
        f32x4 b0 = *(const f32x4*)(projb + pc * 32 + g * 4);
        f32x4 b1 = *(const f32x4*)(projb + pc * 32 + 16 + g * 4);
        half4 h0, h1;
#pragma unroll
        for (int r = 0; r < 4; ++r) {
            float x0 = a0[r] + b0[r];
            h0[r] = (f16)(0.5f * x0 * (1.f + erff(x0 * 0.70710678118f)));
            float x1 = a1[r] + b1[r];
            h1[r] = (f16)(0.5f * x1 * (1.f + erff(x1 * 0.70710678118f)));
        }
        f16* grow = G + (win * 16 + c) * 256 + pc * 32;
        *(half4*)(grow + g * 4) = h0;
        *(half4*)(grow + 16 + g * 4) = h1;
        if (pc < 7) __syncthreads();
    }
}

// ---------------- k4: residual + NCHW scatter, one block per full (bb,h) row ----------------
__global__ __launch_bounds__(256, 8)
void k4_out(const f16* __restrict__ G, const float* __restrict__ feat, float* __restrict__ outp) {
    const int tid = threadIdx.x;
    const int bid = blockIdx.x;            // bb*127 + h
    const int bb = bid / 127, h = bid % 127;
    const int w = tid & 127;               // 0..127 (w==127 masked: pad column)
    const int cq = tid >> 7;               // 0..1
    const bool wok = (w < 127);
    const size_t bbase = (size_t)bb * (256 * 127 * 127);
    const int wi = h >> 2, hh = h & 3;
    const int jh = w >> 5, wl4 = (w >> 2) & 7, e = w & 3;
    const size_t t = ((size_t)((bb * 32 + wi) * 4 + jh)) * 128 + wl4 * 16 + hh * 4 + e;
    const f16* gp = G + t * 256;
    const float* fp = feat + bbase + (size_t)h * 127 + w;
    float* op = outp + bbase + (size_t)h * 127 + w;
#pragma unroll 4
    for (int ci = 0; ci < 32; ++ci) {
        const int ch = ci * 8 + cq * 4;
        if (wok) {
            half4 g4 = *(const half4*)(gp + ch);
#pragma unroll
            for (int j = 0; j < 4; ++j) {
                size_t off = (size_t)(ch + j) * 16129;
                op[off] = fp[off] + (float)g4[j];
            }
        }
    }
}

extern "C" void kernel_launch(void* const* d_in, const int* in_sizes, int n_in,
                              void* d_out, int out_size, void* d_ws, size_t ws_size,
                              hipStream_t stream) {
    const float* feat   = (const float*)d_in[0];
    const float* ln_w   = (const float*)d_in[1];
    const float* ln_b   = (const float*)d_in[2];
    const float* in_w   = (const float*)d_in[3];
    const float* in_b   = (const float*)d_in[4];
    const float* out_w  = (const float*)d_in[5];
    const float* out_b  = (const float*)d_in[6];
    const float* proj_w = (const float*)d_in[7];
    const float* proj_b = (const float*)d_in[8];

    f16* W  = (f16*)d_ws;
    f16* Xb  = W + X0;
    f16* QKb = W + QK0;
    f16* VTb = W + VT0;
    f16* Gb  = Xb;   // reuse X region for G (X dead after k2)

    k0_cast<<<768, 256, 0, stream>>>(in_w, out_w, proj_w, W);
    k1_pack<<<1024, 256, 0, stream>>>(feat, ln_w, ln_b, Xb);
    k2_qkv<<<6144, 256, 0, stream>>>(Xb, W + W_IN0, in_b, QKb, VTb);
    k3_attn<<<2048, 256, 0, stream>>>(QKb, VTb, W + W_OUT0, W + W_PROJ0, out_b, proj_b, Gb);
    k4_out<<<1016, 256, 0, stream>>>(Gb, feat, (float*)d_out);
}